// Round 1
// baseline (577.423 us; speedup 1.0000x reference)
//
#include <hip/hip_runtime.h>
#include <math.h>

namespace {
constexpr int Bn = 2, Hh = 48, Ww = 96, Cch = 128;
constexpr int Nn = Hh * Ww;            // 4608
constexpr int NHh = 8;
constexpr int DSELF = 146, ESELF = 147, DCROSS = 130;
constexpr int Mrows = Bn * Nn;         // 9216
constexpr float SCALEf = 0.17677669529663687f; // 32^-0.5
}

__device__ __forceinline__ float wave_bcast_sum(float v) {
#pragma unroll
  for (int off = 32; off > 0; off >>= 1) v += __shfl_down(v, off);
  return __shfl(v, 0);
}

// ---------------------------------------------------------------------------
// prep: xc = [x, field*fs, rpos]; noc = consistency mask; xe = [LN(xc), noc]
// one wave per pixel, 4 waves per block
// ---------------------------------------------------------------------------
__global__ __launch_bounds__(256) void prep_kernel(
    const float* __restrict__ x, const float* __restrict__ rpos,
    const float* __restrict__ field, const float* __restrict__ fs,
    const float* __restrict__ n0g, const float* __restrict__ n0b,
    float* __restrict__ xc, float* __restrict__ xe) {
  int wv = threadIdx.x >> 6, lane = threadIdx.x & 63;
  int pix = blockIdx.x * 4 + wv;
  int b = pix / Nn, n = pix - b * Nn;
  int py = n / Ww, px = n - py * Ww;
  const float* xrow = x + (size_t)pix * Cch;
  const float* rrow = rpos + (size_t)pix * 16;
  float f0 = field[(size_t)pix * 2 + 0], f1 = field[(size_t)pix * 2 + 1];
  float fsx = fs[0], fsy = fs[1];
  float vals[3];
#pragma unroll
  for (int i = 0; i < 3; i++) {
    int c = lane + i * 64;
    float v = 0.f;
    if (c < Cch) v = xrow[c];
    else if (c == 128) v = f0 * fsx;
    else if (c == 129) v = f1 * fsy;
    else if (c < DSELF) v = rrow[c - 130];
    vals[i] = v;
  }
  float* xcrow = xc + (size_t)pix * DSELF;
#pragma unroll
  for (int i = 0; i < 3; i++) {
    int c = lane + i * 64;
    if (c < DSELF) xcrow[c] = vals[i];
  }
  // two-pass LN over 146
  float s = 0.f;
#pragma unroll
  for (int i = 0; i < 3; i++) { int c = lane + i * 64; if (c < DSELF) s += vals[i]; }
  float mu = wave_bcast_sum(s) * (1.f / DSELF);
  float s2 = 0.f;
#pragma unroll
  for (int i = 0; i < 3; i++) {
    int c = lane + i * 64;
    if (c < DSELF) { float d = vals[i] - mu; s2 += d * d; }
  }
  float var = wave_bcast_sum(s2) * (1.f / DSELF);
  float rs = rsqrtf(var + 1e-5f);
  // consistency mask (lane 0)
  float noc = 0.f;
  if (lane == 0) {
    float ox = fminf(fmaxf(f0 + (float)px, 0.f), (float)(Ww - 1));
    float oy = fminf(fmaxf(f1 + (float)py, 0.f), (float)(Hh - 1));
    float x0f = fminf(fmaxf(floorf(ox), 0.f), (float)(Ww - 2));
    float y0f = fminf(fmaxf(floorf(oy), 0.f), (float)(Hh - 2));
    int x0 = (int)x0f, y0 = (int)y0f;
    float wx = ox - x0f, wy = oy - y0f;
    const float* fo = field + (size_t)(1 - b) * Nn * 2;
    const float* p00 = fo + ((size_t)y0 * Ww + x0) * 2;
    const float* p10 = fo + ((size_t)(y0 + 1) * Ww + x0) * 2;
    float v0 = (1.f - wy) * ((1.f - wx) * p00[0] + wx * p00[2]) +
               wy * ((1.f - wx) * p10[0] + wx * p10[2]);
    float v1 = (1.f - wy) * ((1.f - wx) * p00[1] + wx * p00[3]) +
               wy * ((1.f - wx) * p10[1] + wx * p10[3]);
    float diff = fabsf(f0 + v0) + fabsf(f1 + v1);
    noc = (diff < 2.f) ? 1.f : 0.f;
  }
  noc = __shfl(noc, 0);
  float* xerow = xe + (size_t)pix * ESELF;
#pragma unroll
  for (int i = 0; i < 3; i++) {
    int c = lane + i * 64;
    if (c < DSELF) xerow[c] = (vals[i] - mu) * rs * n0g[c] + n0b[c];
  }
  if (lane == 0) xerow[146] = noc;
}

// ---------------------------------------------------------------------------
// generic fp32 GEMM: C = act(A@W + bias + resid), optional batch-half swap on A
// 64x64 block tile, BK=16, 4x4 per thread
// ---------------------------------------------------------------------------
__global__ __launch_bounds__(256) void gemm_kernel(
    const float* __restrict__ A, const float* __restrict__ Wm,
    const float* __restrict__ bias, const float* __restrict__ resid,
    float* __restrict__ Cm, int M, int N, int K, int swapA, int act) {
  __shared__ float As[16][65];
  __shared__ float Bs[16][68];
  int tid = threadIdx.x;
  int m0 = blockIdx.y * 64, n0 = blockIdx.x * 64;
  int tx = tid & 15, ty = tid >> 4;
  int ar = tid >> 2, kc = (tid & 3) * 4;
  int arow = m0 + ar;
  int asrc = arow;
  if (swapA) asrc = (arow < (M >> 1)) ? arow + (M >> 1) : arow - (M >> 1);
  int bc = tid & 63, br = (tid >> 6) * 4;
  float acc[4][4] = {};
  for (int k0 = 0; k0 < K; k0 += 16) {
#pragma unroll
    for (int i = 0; i < 4; i++) {
      int kk = kc + i;
      As[kk][ar] = (k0 + kk < K) ? A[(size_t)asrc * K + k0 + kk] : 0.f;
    }
#pragma unroll
    for (int i = 0; i < 4; i++) {
      int kk = br + i;
      int kg = k0 + kk;
      Bs[kk][bc] = (kg < K && n0 + bc < N) ? Wm[(size_t)kg * N + n0 + bc] : 0.f;
    }
    __syncthreads();
#pragma unroll
    for (int kk = 0; kk < 16; kk++) {
      float a4[4], b4[4];
#pragma unroll
      for (int i = 0; i < 4; i++) a4[i] = As[kk][ty * 4 + i];
#pragma unroll
      for (int j = 0; j < 4; j++) b4[j] = Bs[kk][tx * 4 + j];
#pragma unroll
      for (int i = 0; i < 4; i++)
#pragma unroll
        for (int j = 0; j < 4; j++) acc[i][j] += a4[i] * b4[j];
    }
    __syncthreads();
  }
#pragma unroll
  for (int i = 0; i < 4; i++) {
    int m = m0 + ty * 4 + i;
#pragma unroll
    for (int j = 0; j < 4; j++) {
      int nn = n0 + tx * 4 + j;
      if (nn >= N) continue;
      float vv = acc[i][j];
      if (bias) vv += bias[nn];
      if (resid) vv += resid[(size_t)m * N + nn];
      if (act == 1) vv = vv / (1.f + expf(-vv));  // silu
      Cm[(size_t)m * N + nn] = vv;
    }
  }
}

// ---------------------------------------------------------------------------
// windowed match attention: one thread per (b, h, n)
// mode 0: offsets from rpos (+coords); mode 1: ox from xc2 ch128 / fs, oy = y
// ---------------------------------------------------------------------------
__global__ __launch_bounds__(256) void attn_kernel(
    const float* __restrict__ q, const float* __restrict__ k,
    const float* __restrict__ v, const float* __restrict__ rpos,
    const float* __restrict__ xc2, const float* __restrict__ fs,
    float* __restrict__ o, float* __restrict__ af_out, int af_stride, int mode) {
  int t = blockIdx.x * 256 + threadIdx.x;
  if (t >= Bn * NHh * Nn) return;
  int n = t % Nn;
  int bh = t / Nn;
  int h = bh % NHh;
  int b = bh / NHh;
  int py = n / Ww, px = n - py * Ww;
  size_t row = (size_t)(b * Nn + n);
  float ox, oy;
  if (mode == 0) {
    ox = rpos[row * 16 + 2 * h] + (float)px;
    oy = rpos[row * 16 + 2 * h + 1] + (float)py;
  } else {
    ox = xc2[row * DCROSS + 128] / fs[0] + (float)px;
    oy = (float)py;  // field1.y is zeroed in reference
  }
  ox = fminf(fmaxf(ox, 1.0f), 93.999f);   // W-1-r-0.001
  oy = fminf(fmaxf(oy, 1.0f), 45.999f);   // H-1-r-0.001
  float mxf = floorf(ox), myf = floorf(oy);
  float fx = ox - mxf, fy = oy - myf;
  int mx = (int)mxf, my = (int)myf;

  float qr[32];
  const float4* q4 = reinterpret_cast<const float4*>(q + row * 256 + h * 32);
#pragma unroll
  for (int i = 0; i < 8; i++) {
    float4 a = q4[i];
    qr[4 * i] = a.x; qr[4 * i + 1] = a.y; qr[4 * i + 2] = a.z; qr[4 * i + 3] = a.w;
  }
  int idx16[16];
  float s[16];
#pragma unroll
  for (int j = 0; j < 4; j++) {
    int gy = my - 1 + j;
#pragma unroll
    for (int i = 0; i < 4; i++) {
      int gx = mx - 1 + i;
      int idx = gy * Ww + gx;  // provably in [0, N-1] given clip constants
      idx16[j * 4 + i] = idx;
      const float4* k4 =
          reinterpret_cast<const float4*>(k + ((size_t)b * Nn + idx) * 256 + h * 32);
      float acc = 0.f;
#pragma unroll
      for (int d = 0; d < 8; d++) {
        float4 kv = k4[d];
        acc += qr[4 * d] * kv.x + qr[4 * d + 1] * kv.y + qr[4 * d + 2] * kv.z +
               qr[4 * d + 3] * kv.w;
      }
      s[j * 4 + i] = acc * SCALEf;
    }
  }
  float w00 = (1.f - fy) * (1.f - fx), w01 = (1.f - fy) * fx;
  float w10 = fy * (1.f - fx), w11 = fy * fx;
  float sc[9];
#pragma unroll
  for (int j = 0; j < 3; j++)
#pragma unroll
    for (int i = 0; i < 3; i++)
      sc[j * 3 + i] = w00 * s[j * 4 + i] + w01 * s[j * 4 + i + 1] +
                      w10 * s[(j + 1) * 4 + i] + w11 * s[(j + 1) * 4 + i + 1];
  float mval = sc[0];
#pragma unroll
  for (int i = 1; i < 9; i++) mval = fmaxf(mval, sc[i]);
  float p[9], psum = 0.f;
#pragma unroll
  for (int i = 0; i < 9; i++) { p[i] = expf(sc[i] - mval); psum += p[i]; }
  float inv = 1.f / psum;
#pragma unroll
  for (int i = 0; i < 9; i++) p[i] *= inv;
  float Ag[16] = {};
#pragma unroll
  for (int j = 0; j < 3; j++)
#pragma unroll
    for (int i = 0; i < 3; i++) {
      float pv = p[j * 3 + i];
      Ag[j * 4 + i] += w00 * pv;
      Ag[j * 4 + i + 1] += w01 * pv;
      Ag[(j + 1) * 4 + i] += w10 * pv;
      Ag[(j + 1) * 4 + i + 1] += w11 * pv;
    }
  float outv[32] = {};
#pragma unroll
  for (int a = 0; a < 16; a++) {
    float w = Ag[a];
    const float4* v4 =
        reinterpret_cast<const float4*>(v + ((size_t)b * Nn + idx16[a]) * 256 + h * 32);
#pragma unroll
    for (int d = 0; d < 8; d++) {
      float4 vv = v4[d];
      outv[4 * d] += w * vv.x; outv[4 * d + 1] += w * vv.y;
      outv[4 * d + 2] += w * vv.z; outv[4 * d + 3] += w * vv.w;
    }
  }
  float4* o4 = reinterpret_cast<float4*>(o + row * 256 + h * 32);
#pragma unroll
  for (int i = 0; i < 8; i++) {
    float4 wv;
    wv.x = outv[4 * i]; wv.y = outv[4 * i + 1];
    wv.z = outv[4 * i + 2]; wv.w = outv[4 * i + 3];
    o4[i] = wv;
  }
  if (af_out) {
#pragma unroll
    for (int a = 0; a < 16; a++) af_out[row * af_stride + h * 16 + a] = Ag[a];
  }
}

// ---------------------------------------------------------------------------
// post self-attn: read xc_new(146), emit rpos_out, xc2(130, ch129=0), h1=LN(xc2)
// ---------------------------------------------------------------------------
__global__ __launch_bounds__(256) void post_self_kernel(
    const float* __restrict__ xcn, const float* __restrict__ n1g,
    const float* __restrict__ n1b, float* __restrict__ out_rpos,
    float* __restrict__ xc2, float* __restrict__ h1) {
  int wv = threadIdx.x >> 6, lane = threadIdx.x & 63;
  int pix = blockIdx.x * 4 + wv;
  const float* row = xcn + (size_t)pix * DSELF;
  float vals[3];
#pragma unroll
  for (int i = 0; i < 3; i++) {
    int c = lane + i * 64;
    vals[i] = (c < DSELF) ? row[c] : 0.f;
  }
#pragma unroll
  for (int i = 0; i < 3; i++) {
    int c = lane + i * 64;
    if (c >= 130 && c < 146) out_rpos[(size_t)pix * 16 + (c - 130)] = vals[i];
  }
#pragma unroll
  for (int i = 0; i < 3; i++) {
    int c = lane + i * 64;
    if (c == 129) vals[i] = 0.f;
  }
  float* x2row = xc2 + (size_t)pix * DCROSS;
#pragma unroll
  for (int i = 0; i < 3; i++) {
    int c = lane + i * 64;
    if (c < DCROSS) x2row[c] = vals[i];
  }
  float s = 0.f;
#pragma unroll
  for (int i = 0; i < 3; i++) { int c = lane + i * 64; if (c < DCROSS) s += vals[i]; }
  float mu = wave_bcast_sum(s) * (1.f / DCROSS);
  float s2 = 0.f;
#pragma unroll
  for (int i = 0; i < 3; i++) {
    int c = lane + i * 64;
    if (c < DCROSS) { float d = vals[i] - mu; s2 += d * d; }
  }
  float var = wave_bcast_sum(s2) * (1.f / DCROSS);
  float rs = rsqrtf(var + 1e-5f);
  float* h1row = h1 + (size_t)pix * DCROSS;
#pragma unroll
  for (int i = 0; i < 3; i++) {
    int c = lane + i * 64;
    if (c < DCROSS) h1row[c] = (vals[i] - mu) * rs * n1g[c] + n1b[c];
  }
}

// ---------------------------------------------------------------------------
// post cross-attn: read xc2_new(130), emit field2, xo_base(128), h2=LN(xo_base)
// ---------------------------------------------------------------------------
__global__ __launch_bounds__(256) void post_cross_kernel(
    const float* __restrict__ xc2n, const float* __restrict__ fs,
    const float* __restrict__ n2g, const float* __restrict__ n2b,
    float* __restrict__ out_f2, float* __restrict__ xob, float* __restrict__ h2) {
  int wv = threadIdx.x >> 6, lane = threadIdx.x & 63;
  int pix = blockIdx.x * 4 + wv;
  const float* row = xc2n + (size_t)pix * DCROSS;
  float vals[3];
#pragma unroll
  for (int i = 0; i < 3; i++) {
    int c = lane + i * 64;
    vals[i] = (c < DCROSS) ? row[c] : 0.f;
  }
  // field2 (ch129 zeroed before division)
  if (lane == 0) out_f2[(size_t)pix * 2 + 0] = vals[2] / fs[0];  // c==128
  if (lane == 1) out_f2[(size_t)pix * 2 + 1] = 0.f;              // c==129 -> 0
  float* xrow = xob + (size_t)pix * Cch;
#pragma unroll
  for (int i = 0; i < 2; i++) {
    int c = lane + i * 64;
    xrow[c] = vals[i];
  }
  float s = vals[0] + vals[1];
  float mu = wave_bcast_sum(s) * (1.f / Cch);
  float d0 = vals[0] - mu, d1 = vals[1] - mu;
  float var = wave_bcast_sum(d0 * d0 + d1 * d1) * (1.f / Cch);
  float rs = rsqrtf(var + 1e-5f);
  float* h2row = h2 + (size_t)pix * Cch;
#pragma unroll
  for (int i = 0; i < 2; i++) {
    int c = lane + i * 64;
    h2row[c] = (vals[i] - mu) * rs * n2g[c] + n2b[c];
  }
}

// ocat[:, 0:256] = g * o  (ocat row stride 384)
__global__ __launch_bounds__(256) void gmul_kernel(const float* __restrict__ g,
                                                   const float* __restrict__ o,
                                                   float* __restrict__ ocat) {
  int t = blockIdx.x * 256 + threadIdx.x;
  int c = t & 255;
  int pix = t >> 8;
  ocat[(size_t)pix * 384 + c] = g[t] * o[t];
}

// depthwise 3x3 SAME on u[:, :256], + bias, exact gelu, * u[:, 256:512]
__global__ __launch_bounds__(256) void dwconv_kernel(
    const float* __restrict__ u, const float* __restrict__ dww,
    const float* __restrict__ dwb, float* __restrict__ aout) {
  int t = blockIdx.x * 256 + threadIdx.x;
  int c = t & 255;
  int pix = t >> 8;
  int b = pix / Nn, n = pix - b * Nn;
  int py = n / Ww, px = n - py * Ww;
  float acc = dwb[c];
#pragma unroll
  for (int ky = 0; ky < 3; ky++) {
    int yy = py + ky - 1;
    if (yy < 0 || yy >= Hh) continue;
#pragma unroll
    for (int kx = 0; kx < 3; kx++) {
      int xx = px + kx - 1;
      if (xx < 0 || xx >= Ww) continue;
      acc += u[((size_t)(b * Nn + yy * Ww + xx)) * 512 + c] * dww[(ky * 3 + kx) * 256 + c];
    }
  }
  float ge = 0.5f * acc * (1.f + erff(acc * 0.70710678118654752f));
  aout[(size_t)pix * 256 + c] = ge * u[(size_t)pix * 512 + 256 + c];
}

extern "C" void kernel_launch(void* const* d_in, const int* in_sizes, int n_in,
                              void* d_out, int out_size, void* d_ws, size_t ws_size,
                              hipStream_t stream) {
  (void)in_sizes; (void)n_in; (void)out_size; (void)ws_size;
  const float* x    = (const float*)d_in[0];
  const float* rpos = (const float*)d_in[1];
  const float* field= (const float*)d_in[2];
  const float* fs   = (const float*)d_in[3];
  const float* n0g  = (const float*)d_in[4];
  const float* n0b  = (const float*)d_in[5];
  const float* n1g  = (const float*)d_in[6];
  const float* n1b  = (const float*)d_in[7];
  const float* n2g  = (const float*)d_in[8];
  const float* n2b  = (const float*)d_in[9];
  const float* sq_w = (const float*)d_in[10];
  const float* sk_w = (const float*)d_in[11];
  const float* sv_w = (const float*)d_in[12];
  const float* sp_w = (const float*)d_in[13];
  const float* cq_w = (const float*)d_in[14];
  const float* ck_w = (const float*)d_in[15];
  const float* cv_w = (const float*)d_in[16];
  const float* cg_w = (const float*)d_in[17];
  const float* cp_w = (const float*)d_in[18];
  const float* fc1w = (const float*)d_in[19];
  const float* fc1b = (const float*)d_in[20];
  const float* dww  = (const float*)d_in[21];
  const float* dwb  = (const float*)d_in[22];
  const float* fc2w = (const float*)d_in[23];
  const float* fc2b = (const float*)d_in[24];

  float* ws = (float*)d_ws;
  float* xc   = ws + 0;         // 1,345,536   (later: xo_base 1,179,648)
  float* xe   = ws + 1345536;   // 1,354,752   (later: po 1,345,536; h2 1,179,648)
  float* q    = ws + 2700288;   // 2,359,296   (later: u spans q+k = 4,718,592)
  float* k    = ws + 5059584;   // 2,359,296
  float* v    = ws + 7418880;   // 2,359,296   (later: pc 1,198,080)
  float* o    = ws + 9778176;   // 2,359,296   (later: aconv 2,359,296)
  float* xc2  = ws + 12137472;  // 1,198,080
  float* h1   = ws + 13335552;  // 1,198,080
  float* g    = ws + 14533632;  // 2,359,296
  float* ocat = ws + 16892928;  // 3,538,944   (total 20,431,872 floats = 81.7 MB)

  float* out_xo   = (float*)d_out;
  float* out_rpos = out_xo + 1179648;
  float* out_f2   = out_xo + 1327104;

  dim3 blk(256);
  auto gemm = [&](const float* A, const float* Wm, const float* bias,
                  const float* resid, float* Cm, int N, int K, int swapA, int act) {
    dim3 grid((N + 63) / 64, Mrows / 64);
    gemm_kernel<<<grid, blk, 0, stream>>>(A, Wm, bias, resid, Cm, Mrows, N, K, swapA, act);
  };

  prep_kernel<<<2304, blk, 0, stream>>>(x, rpos, field, fs, n0g, n0b, xc, xe);
  gemm(xe, sq_w, nullptr, nullptr, q, 256, 147, 0, 0);
  gemm(xe, sk_w, nullptr, nullptr, k, 256, 147, 0, 0);
  gemm(xe, sv_w, nullptr, nullptr, v, 256, 147, 0, 0);
  attn_kernel<<<288, blk, 0, stream>>>(q, k, v, rpos, nullptr, fs, o, nullptr, 0, 0);
  gemm(o, sp_w, nullptr, xc, xe /*xc_new*/, 146, 256, 0, 0);
  post_self_kernel<<<2304, blk, 0, stream>>>(xe, n1g, n1b, out_rpos, xc2, h1);
  gemm(h1, cq_w, nullptr, nullptr, q, 256, 130, 0, 0);
  gemm(h1, ck_w, nullptr, nullptr, k, 256, 130, 1, 0);
  gemm(h1, cv_w, nullptr, nullptr, v, 256, 130, 1, 0);
  gemm(h1, cg_w, nullptr, nullptr, g, 256, 130, 0, 1);
  attn_kernel<<<288, blk, 0, stream>>>(q, k, v, nullptr, xc2, fs, o, ocat + 256, 384, 1);
  gmul_kernel<<<9216, blk, 0, stream>>>(g, o, ocat);
  gemm(ocat, cp_w, nullptr, xc2, v /*xc2_new*/, 130, 384, 0, 0);
  post_cross_kernel<<<2304, blk, 0, stream>>>(v, fs, n2g, n2b, out_f2, xc /*xo_base*/, xe /*h2*/);
  gemm(xe /*h2*/, fc1w, fc1b, nullptr, q /*u*/, 512, 128, 0, 0);
  dwconv_kernel<<<9216, blk, 0, stream>>>(q /*u*/, dww, dwb, o /*aconv*/);
  gemm(o /*aconv*/, fc2w, fc2b, xc /*xo_base*/, out_xo, 128, 256, 0, 0);
}

// Round 2
// 475.932 us; speedup vs baseline: 1.2132x; 1.2132x over previous
//
#include <hip/hip_runtime.h>
#include <math.h>

namespace {
constexpr int Bn = 2, Hh = 48, Ww = 96, Cch = 128;
constexpr int Nn = Hh * Ww;            // 4608
constexpr int NHh = 8;
constexpr int DSELF = 146, ESELF = 147, DCROSS = 130;
constexpr int Mrows = Bn * Nn;         // 9216
constexpr float SCALEf = 0.17677669529663687f; // 32^-0.5
}

__device__ __forceinline__ float wave_bcast_sum(float v) {
#pragma unroll
  for (int off = 32; off > 0; off >>= 1) v += __shfl_down(v, off);
  return __shfl(v, 0);
}

// ---------------------------------------------------------------------------
// prep: xc = [x, field*fs, rpos]; noc = consistency mask; xe = [LN(xc), noc]
// one wave per pixel, 4 waves per block
// ---------------------------------------------------------------------------
__global__ __launch_bounds__(256) void prep_kernel(
    const float* __restrict__ x, const float* __restrict__ rpos,
    const float* __restrict__ field, const float* __restrict__ fs,
    const float* __restrict__ n0g, const float* __restrict__ n0b,
    float* __restrict__ xc, float* __restrict__ xe) {
  int wv = threadIdx.x >> 6, lane = threadIdx.x & 63;
  int pix = blockIdx.x * 4 + wv;
  int b = pix / Nn, n = pix - b * Nn;
  int py = n / Ww, px = n - py * Ww;
  const float* xrow = x + (size_t)pix * Cch;
  const float* rrow = rpos + (size_t)pix * 16;
  float f0 = field[(size_t)pix * 2 + 0], f1 = field[(size_t)pix * 2 + 1];
  float fsx = fs[0], fsy = fs[1];
  float vals[3];
#pragma unroll
  for (int i = 0; i < 3; i++) {
    int c = lane + i * 64;
    float v = 0.f;
    if (c < Cch) v = xrow[c];
    else if (c == 128) v = f0 * fsx;
    else if (c == 129) v = f1 * fsy;
    else if (c < DSELF) v = rrow[c - 130];
    vals[i] = v;
  }
  float* xcrow = xc + (size_t)pix * DSELF;
#pragma unroll
  for (int i = 0; i < 3; i++) {
    int c = lane + i * 64;
    if (c < DSELF) xcrow[c] = vals[i];
  }
  float s = 0.f;
#pragma unroll
  for (int i = 0; i < 3; i++) { int c = lane + i * 64; if (c < DSELF) s += vals[i]; }
  float mu = wave_bcast_sum(s) * (1.f / DSELF);
  float s2 = 0.f;
#pragma unroll
  for (int i = 0; i < 3; i++) {
    int c = lane + i * 64;
    if (c < DSELF) { float d = vals[i] - mu; s2 += d * d; }
  }
  float var = wave_bcast_sum(s2) * (1.f / DSELF);
  float rs = rsqrtf(var + 1e-5f);
  float noc = 0.f;
  if (lane == 0) {
    float ox = fminf(fmaxf(f0 + (float)px, 0.f), (float)(Ww - 1));
    float oy = fminf(fmaxf(f1 + (float)py, 0.f), (float)(Hh - 1));
    float x0f = fminf(fmaxf(floorf(ox), 0.f), (float)(Ww - 2));
    float y0f = fminf(fmaxf(floorf(oy), 0.f), (float)(Hh - 2));
    int x0 = (int)x0f, y0 = (int)y0f;
    float wx = ox - x0f, wy = oy - y0f;
    const float* fo = field + (size_t)(1 - b) * Nn * 2;
    const float* p00 = fo + ((size_t)y0 * Ww + x0) * 2;
    const float* p10 = fo + ((size_t)(y0 + 1) * Ww + x0) * 2;
    float v0 = (1.f - wy) * ((1.f - wx) * p00[0] + wx * p00[2]) +
               wy * ((1.f - wx) * p10[0] + wx * p10[2]);
    float v1 = (1.f - wy) * ((1.f - wx) * p00[1] + wx * p00[3]) +
               wy * ((1.f - wx) * p10[1] + wx * p10[3]);
    float diff = fabsf(f0 + v0) + fabsf(f1 + v1);
    noc = (diff < 2.f) ? 1.f : 0.f;
  }
  noc = __shfl(noc, 0);
  float* xerow = xe + (size_t)pix * ESELF;
#pragma unroll
  for (int i = 0; i < 3; i++) {
    int c = lane + i * 64;
    if (c < DSELF) xerow[c] = (vals[i] - mu) * rs * n0g[c] + n0b[c];
  }
  if (lane == 0) xerow[146] = noc;
}

// ---------------------------------------------------------------------------
// generic fp32 GEMM: C = act(A@W + bias + resid), optional batch-half swap on A
// ---------------------------------------------------------------------------
__global__ __launch_bounds__(256) void gemm_kernel(
    const float* __restrict__ A, const float* __restrict__ Wm,
    const float* __restrict__ bias, const float* __restrict__ resid,
    float* __restrict__ Cm, int M, int N, int K, int swapA, int act) {
  __shared__ float As[16][65];
  __shared__ float Bs[16][68];
  int tid = threadIdx.x;
  int m0 = blockIdx.y * 64, n0 = blockIdx.x * 64;
  int tx = tid & 15, ty = tid >> 4;
  int ar = tid >> 2, kc = (tid & 3) * 4;
  int arow = m0 + ar;
  int asrc = arow;
  if (swapA) asrc = (arow < (M >> 1)) ? arow + (M >> 1) : arow - (M >> 1);
  int bc = tid & 63, br = (tid >> 6) * 4;
  float acc[4][4] = {};
  for (int k0 = 0; k0 < K; k0 += 16) {
#pragma unroll
    for (int i = 0; i < 4; i++) {
      int kk = kc + i;
      As[kk][ar] = (k0 + kk < K) ? A[(size_t)asrc * K + k0 + kk] : 0.f;
    }
#pragma unroll
    for (int i = 0; i < 4; i++) {
      int kk = br + i;
      int kg = k0 + kk;
      Bs[kk][bc] = (kg < K && n0 + bc < N) ? Wm[(size_t)kg * N + n0 + bc] : 0.f;
    }
    __syncthreads();
#pragma unroll
    for (int kk = 0; kk < 16; kk++) {
      float a4[4], b4[4];
#pragma unroll
      for (int i = 0; i < 4; i++) a4[i] = As[kk][ty * 4 + i];
#pragma unroll
      for (int j = 0; j < 4; j++) b4[j] = Bs[kk][tx * 4 + j];
#pragma unroll
      for (int i = 0; i < 4; i++)
#pragma unroll
        for (int j = 0; j < 4; j++) acc[i][j] += a4[i] * b4[j];
    }
    __syncthreads();
  }
#pragma unroll
  for (int i = 0; i < 4; i++) {
    int m = m0 + ty * 4 + i;
#pragma unroll
    for (int j = 0; j < 4; j++) {
      int nn = n0 + tx * 4 + j;
      if (nn >= N) continue;
      float vv = acc[i][j];
      if (bias) vv += bias[nn];
      if (resid) vv += resid[(size_t)m * N + nn];
      if (act == 1) vv = vv / (1.f + expf(-vv));  // silu
      Cm[(size_t)m * N + nn] = vv;
    }
  }
}

// ---------------------------------------------------------------------------
// windowed match attention, one WAVE per pixel; lane = h*8 + c covers float4
// c of head h. QK dot via 3x shfl_xor in 8-lane head group; softmax redundant
// per lane; PV accumulates one float4/lane. Optional fused g-multiply and
// Af output (cross attention).
// ---------------------------------------------------------------------------
__global__ __launch_bounds__(256) void attn_wave_kernel(
    const float* __restrict__ q, const float* __restrict__ k,
    const float* __restrict__ v, const float* __restrict__ rpos,
    const float* __restrict__ xc2, const float* __restrict__ fs,
    const float* __restrict__ g, float* __restrict__ o, int o_stride,
    float* __restrict__ af_out, int mode) {
  int wv = threadIdx.x >> 6, lane = threadIdx.x & 63;
  int pix = blockIdx.x * 4 + wv;
  int b = pix / Nn, n = pix - b * Nn;
  int py = n / Ww, px = n - py * Ww;
  int h = lane >> 3, c = lane & 7;
  size_t row = (size_t)pix;
  float ox, oy;
  if (mode == 0) {
    ox = rpos[row * 16 + 2 * h] + (float)px;
    oy = rpos[row * 16 + 2 * h + 1] + (float)py;
  } else {
    ox = xc2[row * DCROSS + 128] / fs[0] + (float)px;
    oy = (float)py;  // field1.y zeroed in reference
  }
  ox = fminf(fmaxf(ox, 1.0f), 93.999f);
  oy = fminf(fmaxf(oy, 1.0f), 45.999f);
  float mxf = floorf(ox), myf = floorf(oy);
  float fx = ox - mxf, fy = oy - myf;
  int mx = (int)mxf, my = (int)myf;
  int base = b * Nn;

  float4 qv = *reinterpret_cast<const float4*>(q + row * 256 + lane * 4);
  float s[16];
#pragma unroll
  for (int j = 0; j < 4; j++) {
    int gy = my - 1 + j;
#pragma unroll
    for (int i = 0; i < 4; i++) {
      int gx = mx - 1 + i;
      int idx = gy * Ww + gx;  // in-bounds by clip constants
      float4 kv = *reinterpret_cast<const float4*>(
          k + (size_t)(base + idx) * 256 + lane * 4);
      float d = qv.x * kv.x + qv.y * kv.y + qv.z * kv.z + qv.w * kv.w;
      d += __shfl_xor(d, 1);
      d += __shfl_xor(d, 2);
      d += __shfl_xor(d, 4);
      s[j * 4 + i] = d * SCALEf;
    }
  }
  float w00 = (1.f - fy) * (1.f - fx), w01 = (1.f - fy) * fx;
  float w10 = fy * (1.f - fx), w11 = fy * fx;
  float sc[9];
#pragma unroll
  for (int j = 0; j < 3; j++)
#pragma unroll
    for (int i = 0; i < 3; i++)
      sc[j * 3 + i] = w00 * s[j * 4 + i] + w01 * s[j * 4 + i + 1] +
                      w10 * s[(j + 1) * 4 + i] + w11 * s[(j + 1) * 4 + i + 1];
  float mval = sc[0];
#pragma unroll
  for (int i = 1; i < 9; i++) mval = fmaxf(mval, sc[i]);
  float p[9], psum = 0.f;
#pragma unroll
  for (int i = 0; i < 9; i++) { p[i] = expf(sc[i] - mval); psum += p[i]; }
  float inv = 1.f / psum;
#pragma unroll
  for (int i = 0; i < 9; i++) p[i] *= inv;
  float Ag[16] = {};
#pragma unroll
  for (int j = 0; j < 3; j++)
#pragma unroll
    for (int i = 0; i < 3; i++) {
      float pv = p[j * 3 + i];
      Ag[j * 4 + i] += w00 * pv;
      Ag[j * 4 + i + 1] += w01 * pv;
      Ag[(j + 1) * 4 + i] += w10 * pv;
      Ag[(j + 1) * 4 + i + 1] += w11 * pv;
    }
  float4 acc = make_float4(0.f, 0.f, 0.f, 0.f);
#pragma unroll
  for (int j = 0; j < 4; j++) {
    int gy = my - 1 + j;
#pragma unroll
    for (int i = 0; i < 4; i++) {
      int gx = mx - 1 + i;
      int idx = gy * Ww + gx;
      float4 vv = *reinterpret_cast<const float4*>(
          v + (size_t)(base + idx) * 256 + lane * 4);
      float w = Ag[j * 4 + i];
      acc.x += w * vv.x; acc.y += w * vv.y; acc.z += w * vv.z; acc.w += w * vv.w;
    }
  }
  if (g) {
    float4 gg = *reinterpret_cast<const float4*>(g + row * 256 + lane * 4);
    acc.x *= gg.x; acc.y *= gg.y; acc.z *= gg.z; acc.w *= gg.w;
  }
  *reinterpret_cast<float4*>(o + row * o_stride + lane * 4) = acc;
  if (af_out) {
    float a0 = 0.f, a1 = 0.f;
#pragma unroll
    for (int a = 0; a < 8; a++) {  // static-index select (avoid scratch)
      if (c == a) { a0 = Ag[2 * a]; a1 = Ag[2 * a + 1]; }
    }
    *reinterpret_cast<float2*>(af_out + row * o_stride + h * 16 + 2 * c) =
        make_float2(a0, a1);
  }
}

// ---------------------------------------------------------------------------
// post self-attn: read xc_new(146), emit rpos_out, xc2(130, ch129=0), h1=LN(xc2)
// ---------------------------------------------------------------------------
__global__ __launch_bounds__(256) void post_self_kernel(
    const float* __restrict__ xcn, const float* __restrict__ n1g,
    const float* __restrict__ n1b, float* __restrict__ out_rpos,
    float* __restrict__ xc2, float* __restrict__ h1) {
  int wv = threadIdx.x >> 6, lane = threadIdx.x & 63;
  int pix = blockIdx.x * 4 + wv;
  const float* row = xcn + (size_t)pix * DSELF;
  float vals[3];
#pragma unroll
  for (int i = 0; i < 3; i++) {
    int c = lane + i * 64;
    vals[i] = (c < DSELF) ? row[c] : 0.f;
  }
#pragma unroll
  for (int i = 0; i < 3; i++) {
    int c = lane + i * 64;
    if (c >= 130 && c < 146) out_rpos[(size_t)pix * 16 + (c - 130)] = vals[i];
  }
#pragma unroll
  for (int i = 0; i < 3; i++) {
    int c = lane + i * 64;
    if (c == 129) vals[i] = 0.f;
  }
  float* x2row = xc2 + (size_t)pix * DCROSS;
#pragma unroll
  for (int i = 0; i < 3; i++) {
    int c = lane + i * 64;
    if (c < DCROSS) x2row[c] = vals[i];
  }
  float s = 0.f;
#pragma unroll
  for (int i = 0; i < 3; i++) { int c = lane + i * 64; if (c < DCROSS) s += vals[i]; }
  float mu = wave_bcast_sum(s) * (1.f / DCROSS);
  float s2 = 0.f;
#pragma unroll
  for (int i = 0; i < 3; i++) {
    int c = lane + i * 64;
    if (c < DCROSS) { float d = vals[i] - mu; s2 += d * d; }
  }
  float var = wave_bcast_sum(s2) * (1.f / DCROSS);
  float rs = rsqrtf(var + 1e-5f);
  float* h1row = h1 + (size_t)pix * DCROSS;
#pragma unroll
  for (int i = 0; i < 3; i++) {
    int c = lane + i * 64;
    if (c < DCROSS) h1row[c] = (vals[i] - mu) * rs * n1g[c] + n1b[c];
  }
}

// ---------------------------------------------------------------------------
// post cross-attn: read xc2_new(130), emit field2, xo_base(128), h2=LN(xo_base)
// ---------------------------------------------------------------------------
__global__ __launch_bounds__(256) void post_cross_kernel(
    const float* __restrict__ xc2n, const float* __restrict__ fs,
    const float* __restrict__ n2g, const float* __restrict__ n2b,
    float* __restrict__ out_f2, float* __restrict__ xob, float* __restrict__ h2) {
  int wv = threadIdx.x >> 6, lane = threadIdx.x & 63;
  int pix = blockIdx.x * 4 + wv;
  const float* row = xc2n + (size_t)pix * DCROSS;
  float vals[3];
#pragma unroll
  for (int i = 0; i < 3; i++) {
    int c = lane + i * 64;
    vals[i] = (c < DCROSS) ? row[c] : 0.f;
  }
  if (lane == 0) out_f2[(size_t)pix * 2 + 0] = vals[2] / fs[0];  // c==128
  if (lane == 1) out_f2[(size_t)pix * 2 + 1] = 0.f;              // c==129 -> 0
  float* xrow = xob + (size_t)pix * Cch;
#pragma unroll
  for (int i = 0; i < 2; i++) {
    int c = lane + i * 64;
    xrow[c] = vals[i];
  }
  float s = vals[0] + vals[1];
  float mu = wave_bcast_sum(s) * (1.f / Cch);
  float d0 = vals[0] - mu, d1 = vals[1] - mu;
  float var = wave_bcast_sum(d0 * d0 + d1 * d1) * (1.f / Cch);
  float rs = rsqrtf(var + 1e-5f);
  float* h2row = h2 + (size_t)pix * Cch;
#pragma unroll
  for (int i = 0; i < 2; i++) {
    int c = lane + i * 64;
    h2row[c] = (vals[i] - mu) * rs * n2g[c] + n2b[c];
  }
}

// depthwise 3x3 SAME on u[:, :256], + bias, exact gelu, * u[:, 256:512]
__global__ __launch_bounds__(256) void dwconv_kernel(
    const float* __restrict__ u, const float* __restrict__ dww,
    const float* __restrict__ dwb, float* __restrict__ aout) {
  int t = blockIdx.x * 256 + threadIdx.x;
  int c = t & 255;
  int pix = t >> 8;
  int b = pix / Nn, n = pix - b * Nn;
  int py = n / Ww, px = n - py * Ww;
  float acc = dwb[c];
#pragma unroll
  for (int ky = 0; ky < 3; ky++) {
    int yy = py + ky - 1;
    if (yy < 0 || yy >= Hh) continue;
#pragma unroll
    for (int kx = 0; kx < 3; kx++) {
      int xx = px + kx - 1;
      if (xx < 0 || xx >= Ww) continue;
      acc += u[((size_t)(b * Nn + yy * Ww + xx)) * 512 + c] * dww[(ky * 3 + kx) * 256 + c];
    }
  }
  float ge = 0.5f * acc * (1.f + erff(acc * 0.70710678118654752f));
  aout[(size_t)pix * 256 + c] = ge * u[(size_t)pix * 512 + 256 + c];
}

extern "C" void kernel_launch(void* const* d_in, const int* in_sizes, int n_in,
                              void* d_out, int out_size, void* d_ws, size_t ws_size,
                              hipStream_t stream) {
  (void)in_sizes; (void)n_in; (void)out_size; (void)ws_size;
  const float* x    = (const float*)d_in[0];
  const float* rpos = (const float*)d_in[1];
  const float* field= (const float*)d_in[2];
  const float* fs   = (const float*)d_in[3];
  const float* n0g  = (const float*)d_in[4];
  const float* n0b  = (const float*)d_in[5];
  const float* n1g  = (const float*)d_in[6];
  const float* n1b  = (const float*)d_in[7];
  const float* n2g  = (const float*)d_in[8];
  const float* n2b  = (const float*)d_in[9];
  const float* sq_w = (const float*)d_in[10];
  const float* sk_w = (const float*)d_in[11];
  const float* sv_w = (const float*)d_in[12];
  const float* sp_w = (const float*)d_in[13];
  const float* cq_w = (const float*)d_in[14];
  const float* ck_w = (const float*)d_in[15];
  const float* cv_w = (const float*)d_in[16];
  const float* cg_w = (const float*)d_in[17];
  const float* cp_w = (const float*)d_in[18];
  const float* fc1w = (const float*)d_in[19];
  const float* fc1b = (const float*)d_in[20];
  const float* dww  = (const float*)d_in[21];
  const float* dwb  = (const float*)d_in[22];
  const float* fc2w = (const float*)d_in[23];
  const float* fc2b = (const float*)d_in[24];

  float* ws = (float*)d_ws;
  float* xc   = ws + 0;         // 1,345,536   (later: xo_base)
  float* xe   = ws + 1345536;   // 1,354,752   (later: xc_new; h2)
  float* q    = ws + 2700288;   // 2,359,296   (later: u spans q+k)
  float* k    = ws + 5059584;   // 2,359,296
  float* v    = ws + 7418880;   // 2,359,296   (later: xc2_new)
  float* o    = ws + 9778176;   // 2,359,296   (later: aconv)
  float* xc2  = ws + 12137472;  // 1,198,080
  float* h1   = ws + 13335552;  // 1,198,080
  float* g    = ws + 14533632;  // 2,359,296
  float* ocat = ws + 16892928;  // 3,538,944

  float* out_xo   = (float*)d_out;
  float* out_rpos = out_xo + 1179648;
  float* out_f2   = out_xo + 1327104;

  dim3 blk(256);
  auto gemm = [&](const float* A, const float* Wm, const float* bias,
                  const float* resid, float* Cm, int N, int K, int swapA, int act) {
    dim3 grid((N + 63) / 64, Mrows / 64);
    gemm_kernel<<<grid, blk, 0, stream>>>(A, Wm, bias, resid, Cm, Mrows, N, K, swapA, act);
  };

  prep_kernel<<<2304, blk, 0, stream>>>(x, rpos, field, fs, n0g, n0b, xc, xe);
  gemm(xe, sq_w, nullptr, nullptr, q, 256, 147, 0, 0);
  gemm(xe, sk_w, nullptr, nullptr, k, 256, 147, 0, 0);
  gemm(xe, sv_w, nullptr, nullptr, v, 256, 147, 0, 0);
  attn_wave_kernel<<<2304, blk, 0, stream>>>(q, k, v, rpos, nullptr, fs, nullptr,
                                             o, 256, nullptr, 0);
  gemm(o, sp_w, nullptr, xc, xe /*xc_new*/, 146, 256, 0, 0);
  post_self_kernel<<<2304, blk, 0, stream>>>(xe, n1g, n1b, out_rpos, xc2, h1);
  gemm(h1, cq_w, nullptr, nullptr, q, 256, 130, 0, 0);
  gemm(h1, ck_w, nullptr, nullptr, k, 256, 130, 1, 0);
  gemm(h1, cv_w, nullptr, nullptr, v, 256, 130, 1, 0);
  gemm(h1, cg_w, nullptr, nullptr, g, 256, 130, 0, 1);
  attn_wave_kernel<<<2304, blk, 0, stream>>>(q, k, v, nullptr, xc2, fs, g,
                                             ocat, 384, ocat + 256, 1);
  gemm(ocat, cp_w, nullptr, xc2, v /*xc2_new*/, 130, 384, 0, 0);
  post_cross_kernel<<<2304, blk, 0, stream>>>(v, fs, n2g, n2b, out_f2,
                                              xc /*xo_base*/, xe /*h2*/);
  gemm(xe /*h2*/, fc1w, fc1b, nullptr, q /*u*/, 512, 128, 0, 0);
  dwconv_kernel<<<9216, blk, 0, stream>>>(q /*u*/, dww, dwb, o /*aconv*/);
  gemm(o /*aconv*/, fc2w, fc2b, xc /*xo_base*/, out_xo, 128, 256, 0, 0);
}

// Round 3
// 182.791 us; speedup vs baseline: 3.1589x; 2.6037x over previous
//
#include <hip/hip_runtime.h>
#include <math.h>

namespace {
constexpr int Bn = 2, Hh = 48, Ww = 96, Cch = 128;
constexpr int Nn = Hh * Ww;            // 4608
constexpr int NHh = 8;
constexpr int DSELF = 146, ESELF = 147, DCROSS = 130;
constexpr int Mrows = Bn * Nn;         // 9216
constexpr float SCALEf = 0.17677669529663687f; // 32^-0.5
}

typedef float f32x4 __attribute__((ext_vector_type(4)));
typedef short s16x8 __attribute__((ext_vector_type(8)));

__device__ __forceinline__ unsigned short f2b(float f) {
  unsigned int u = __float_as_uint(f);
  u = u + 0x7fffu + ((u >> 16) & 1u);
  return (unsigned short)(u >> 16);
}

__device__ __forceinline__ f32x4 mfma_bf16(s16x8 a, s16x8 b, f32x4 c) {
  f32x4 d;
  asm volatile("v_mfma_f32_16x16x32_bf16 %0, %1, %2, %3"
               : "=&v"(d) : "v"(a), "v"(b), "v"(c));
  return d;
}

__device__ __forceinline__ float wave_bcast_sum(float v) {
#pragma unroll
  for (int off = 32; off > 0; off >>= 1) v += __shfl_down(v, off);
  return __shfl(v, 0);
}

// ---------------------------------------------------------------------------
// weight convert: fp32 W[K][N] -> bf16 Wt[n][Kp] (transposed, K zero-padded)
// ---------------------------------------------------------------------------
struct WDesc { const float* src; int K, N, Kp, dstOff, blkOff; };
struct WPack { WDesc d[11]; };

__global__ __launch_bounds__(256) void convert_w_kernel(WPack p, unsigned short* dst) {
  int bi = blockIdx.x;
  int mi = 0;
#pragma unroll
  for (int i = 1; i < 11; i++) if (bi >= p.d[i].blkOff) mi = i;
  WDesc w = p.d[mi];
  int e = (bi - w.blkOff) * 2048 + threadIdx.x * 8;
  int total = w.N * w.Kp;
  if (e >= total) return;
  int n = e / w.Kp, k0 = e - n * w.Kp;
  s16x8 pack;
#pragma unroll
  for (int j = 0; j < 8; j++) {
    int kk = k0 + j;
    float vv = (kk < w.K) ? w.src[(size_t)kk * w.N + n] : 0.f;
    pack[j] = (short)f2b(vv);
  }
  *reinterpret_cast<s16x8*>(dst + w.dstOff + e) = pack;
}

// ---------------------------------------------------------------------------
// bf16 MFMA GEMM: out(f32) = act(A(bf16,[M][Kp]) @ Wt(bf16,[N][Kp])^T
//                              + bias + resid), optional batch-half swap on A
// 64x64 tile, BK=32, 4 waves each 32x32 (2x2 16x16x32 frags)
// ---------------------------------------------------------------------------
__global__ __launch_bounds__(256) void mfma_gemm_kernel(
    const unsigned short* __restrict__ A, int Kp,
    const unsigned short* __restrict__ Wt, int N,
    const float* __restrict__ bias, const float* __restrict__ resid,
    float* __restrict__ out, int swapA, int act) {
  __shared__ unsigned short As[64 * 40];
  __shared__ unsigned short Bs[64 * 40];
  int tid = threadIdx.x;
  int m0 = blockIdx.y * 64, n0 = blockIdx.x * 64;
  int lane = tid & 63, wv = tid >> 6;
  int wr = wv >> 1, wc = wv & 1;
  int lr = lane & 15, lk = (lane >> 4) * 8;
  int sr = tid >> 2, sk8 = (tid & 3) * 8;
  int am = m0 + sr;
  if (swapA) am = (am < Mrows / 2) ? am + Mrows / 2 : am - Mrows / 2;
  const unsigned short* aptr = A + (size_t)am * Kp + sk8;
  int bn = n0 + sr;
  const unsigned short* bptr = (bn < N) ? Wt + (size_t)bn * Kp + sk8 : nullptr;
  f32x4 acc00 = {}, acc01 = {}, acc10 = {}, acc11 = {};
  for (int k0 = 0; k0 < Kp; k0 += 32) {
    s16x8 av = *reinterpret_cast<const s16x8*>(aptr + k0);
    s16x8 bv = {};
    if (bptr) bv = *reinterpret_cast<const s16x8*>(bptr + k0);
    *reinterpret_cast<s16x8*>(&As[sr * 40 + sk8]) = av;
    *reinterpret_cast<s16x8*>(&Bs[sr * 40 + sk8]) = bv;
    __syncthreads();
    s16x8 a0 = *reinterpret_cast<const s16x8*>(&As[(wr * 32 + lr) * 40 + lk]);
    s16x8 a1 = *reinterpret_cast<const s16x8*>(&As[(wr * 32 + 16 + lr) * 40 + lk]);
    s16x8 b0 = *reinterpret_cast<const s16x8*>(&Bs[(wc * 32 + lr) * 40 + lk]);
    s16x8 b1 = *reinterpret_cast<const s16x8*>(&Bs[(wc * 32 + 16 + lr) * 40 + lk]);
    acc00 = mfma_bf16(a0, b0, acc00);
    acc01 = mfma_bf16(a0, b1, acc01);
    acc10 = mfma_bf16(a1, b0, acc10);
    acc11 = mfma_bf16(a1, b1, acc11);
    __syncthreads();
  }
  int rowBase = m0 + wr * 32 + (lane >> 4) * 4;
  f32x4 accs[2][2] = {{acc00, acc01}, {acc10, acc11}};
#pragma unroll
  for (int fc = 0; fc < 2; fc++) {
    int col = n0 + wc * 32 + fc * 16 + lr;
    if (col >= N) continue;
    float bval = bias ? bias[col] : 0.f;
#pragma unroll
    for (int fr = 0; fr < 2; fr++) {
#pragma unroll
      for (int r = 0; r < 4; r++) {
        int row = rowBase + fr * 16 + r;
        float vv = accs[fr][fc][r] + bval;
        if (resid) vv += resid[(size_t)row * N + col];
        if (act == 1) vv = vv / (1.f + expf(-vv));  // silu
        out[(size_t)row * N + col] = vv;
      }
    }
  }
}

// ---------------------------------------------------------------------------
// prep: xc = [x, field*fs, rpos] (f32); noc mask; xe_b = bf16[LN(xc), noc, 0pad]
// ---------------------------------------------------------------------------
__global__ __launch_bounds__(256) void prep_kernel(
    const float* __restrict__ x, const float* __restrict__ rpos,
    const float* __restrict__ field, const float* __restrict__ fs,
    const float* __restrict__ n0g, const float* __restrict__ n0b,
    float* __restrict__ xc, unsigned short* __restrict__ xe_b) {
  int wv = threadIdx.x >> 6, lane = threadIdx.x & 63;
  int pix = blockIdx.x * 4 + wv;
  int b = pix / Nn, n = pix - b * Nn;
  int py = n / Ww, px = n - py * Ww;
  const float* xrow = x + (size_t)pix * Cch;
  const float* rrow = rpos + (size_t)pix * 16;
  float f0 = field[(size_t)pix * 2 + 0], f1 = field[(size_t)pix * 2 + 1];
  float fsx = fs[0], fsy = fs[1];
  float vals[3];
#pragma unroll
  for (int i = 0; i < 3; i++) {
    int c = lane + i * 64;
    float v = 0.f;
    if (c < Cch) v = xrow[c];
    else if (c == 128) v = f0 * fsx;
    else if (c == 129) v = f1 * fsy;
    else if (c < DSELF) v = rrow[c - 130];
    vals[i] = v;
  }
  float* xcrow = xc + (size_t)pix * DSELF;
#pragma unroll
  for (int i = 0; i < 3; i++) {
    int c = lane + i * 64;
    if (c < DSELF) xcrow[c] = vals[i];
  }
  float s = 0.f;
#pragma unroll
  for (int i = 0; i < 3; i++) { int c = lane + i * 64; if (c < DSELF) s += vals[i]; }
  float mu = wave_bcast_sum(s) * (1.f / DSELF);
  float s2 = 0.f;
#pragma unroll
  for (int i = 0; i < 3; i++) {
    int c = lane + i * 64;
    if (c < DSELF) { float d = vals[i] - mu; s2 += d * d; }
  }
  float var = wave_bcast_sum(s2) * (1.f / DSELF);
  float rs = rsqrtf(var + 1e-5f);
  float noc = 0.f;
  if (lane == 0) {
    float ox = fminf(fmaxf(f0 + (float)px, 0.f), (float)(Ww - 1));
    float oy = fminf(fmaxf(f1 + (float)py, 0.f), (float)(Hh - 1));
    float x0f = fminf(fmaxf(floorf(ox), 0.f), (float)(Ww - 2));
    float y0f = fminf(fmaxf(floorf(oy), 0.f), (float)(Hh - 2));
    int x0 = (int)x0f, y0 = (int)y0f;
    float wx = ox - x0f, wy = oy - y0f;
    const float* fo = field + (size_t)(1 - b) * Nn * 2;
    const float* p00 = fo + ((size_t)y0 * Ww + x0) * 2;
    const float* p10 = fo + ((size_t)(y0 + 1) * Ww + x0) * 2;
    float v0 = (1.f - wy) * ((1.f - wx) * p00[0] + wx * p00[2]) +
               wy * ((1.f - wx) * p10[0] + wx * p10[2]);
    float v1 = (1.f - wy) * ((1.f - wx) * p00[1] + wx * p00[3]) +
               wy * ((1.f - wx) * p10[1] + wx * p10[3]);
    float diff = fabsf(f0 + v0) + fabsf(f1 + v1);
    noc = (diff < 2.f) ? 1.f : 0.f;
  }
  noc = __shfl(noc, 0);
  unsigned short* xerow = xe_b + (size_t)pix * 160;
#pragma unroll
  for (int i = 0; i < 3; i++) {
    int c = lane + i * 64;
    if (c < 160) {
      float v;
      if (c < DSELF) v = (vals[i] - mu) * rs * n0g[c] + n0b[c];
      else if (c == 146) v = noc;
      else v = 0.f;
      xerow[c] = f2b(v);
    }
  }
}

// ---------------------------------------------------------------------------
// windowed match attention, one WAVE per pixel; bf16 outputs.
// ---------------------------------------------------------------------------
__global__ __launch_bounds__(256) void attn_wave_kernel(
    const float* __restrict__ q, const float* __restrict__ k,
    const float* __restrict__ v, const float* __restrict__ rpos,
    const float* __restrict__ xc2, const float* __restrict__ fs,
    const float* __restrict__ g, unsigned short* __restrict__ o, int o_stride,
    int mode) {
  int wv = threadIdx.x >> 6, lane = threadIdx.x & 63;
  int pix = blockIdx.x * 4 + wv;
  int b = pix / Nn, n = pix - b * Nn;
  int py = n / Ww, px = n - py * Ww;
  int h = lane >> 3, c = lane & 7;
  size_t row = (size_t)pix;
  float ox, oy;
  if (mode == 0) {
    ox = rpos[row * 16 + 2 * h] + (float)px;
    oy = rpos[row * 16 + 2 * h + 1] + (float)py;
  } else {
    ox = xc2[row * DCROSS + 128] / fs[0] + (float)px;
    oy = (float)py;
  }
  ox = fminf(fmaxf(ox, 1.0f), 93.999f);
  oy = fminf(fmaxf(oy, 1.0f), 45.999f);
  float mxf = floorf(ox), myf = floorf(oy);
  float fx = ox - mxf, fy = oy - myf;
  int mx = (int)mxf, my = (int)myf;
  int base = b * Nn;

  float4 qv = *reinterpret_cast<const float4*>(q + row * 256 + lane * 4);
  float s[16];
#pragma unroll
  for (int j = 0; j < 4; j++) {
    int gy = my - 1 + j;
#pragma unroll
    for (int i = 0; i < 4; i++) {
      int gx = mx - 1 + i;
      int idx = gy * Ww + gx;
      float4 kv = *reinterpret_cast<const float4*>(
          k + (size_t)(base + idx) * 256 + lane * 4);
      float d = qv.x * kv.x + qv.y * kv.y + qv.z * kv.z + qv.w * kv.w;
      d += __shfl_xor(d, 1);
      d += __shfl_xor(d, 2);
      d += __shfl_xor(d, 4);
      s[j * 4 + i] = d * SCALEf;
    }
  }
  float w00 = (1.f - fy) * (1.f - fx), w01 = (1.f - fy) * fx;
  float w10 = fy * (1.f - fx), w11 = fy * fx;
  float sc[9];
#pragma unroll
  for (int j = 0; j < 3; j++)
#pragma unroll
    for (int i = 0; i < 3; i++)
      sc[j * 3 + i] = w00 * s[j * 4 + i] + w01 * s[j * 4 + i + 1] +
                      w10 * s[(j + 1) * 4 + i] + w11 * s[(j + 1) * 4 + i + 1];
  float mval = sc[0];
#pragma unroll
  for (int i = 1; i < 9; i++) mval = fmaxf(mval, sc[i]);
  float p[9], psum = 0.f;
#pragma unroll
  for (int i = 0; i < 9; i++) { p[i] = expf(sc[i] - mval); psum += p[i]; }
  float inv = 1.f / psum;
#pragma unroll
  for (int i = 0; i < 9; i++) p[i] *= inv;
  float Ag[16] = {};
#pragma unroll
  for (int j = 0; j < 3; j++)
#pragma unroll
    for (int i = 0; i < 3; i++) {
      float pv = p[j * 3 + i];
      Ag[j * 4 + i] += w00 * pv;
      Ag[j * 4 + i + 1] += w01 * pv;
      Ag[(j + 1) * 4 + i] += w10 * pv;
      Ag[(j + 1) * 4 + i + 1] += w11 * pv;
    }
  float4 acc = make_float4(0.f, 0.f, 0.f, 0.f);
#pragma unroll
  for (int j = 0; j < 4; j++) {
    int gy = my - 1 + j;
#pragma unroll
    for (int i = 0; i < 4; i++) {
      int gx = mx - 1 + i;
      int idx = gy * Ww + gx;
      float4 vv = *reinterpret_cast<const float4*>(
          v + (size_t)(base + idx) * 256 + lane * 4);
      float w = Ag[j * 4 + i];
      acc.x += w * vv.x; acc.y += w * vv.y; acc.z += w * vv.z; acc.w += w * vv.w;
    }
  }
  if (g) {
    float4 gg = *reinterpret_cast<const float4*>(g + row * 256 + lane * 4);
    acc.x *= gg.x; acc.y *= gg.y; acc.z *= gg.z; acc.w *= gg.w;
  }
  unsigned int p0 = (unsigned int)f2b(acc.x) | ((unsigned int)f2b(acc.y) << 16);
  unsigned int p1 = (unsigned int)f2b(acc.z) | ((unsigned int)f2b(acc.w) << 16);
  *reinterpret_cast<uint2*>(o + row * o_stride + lane * 4) = make_uint2(p0, p1);
  if (mode == 1) {
    float a0 = 0.f, a1 = 0.f;
#pragma unroll
    for (int a = 0; a < 8; a++) {
      if (c == a) { a0 = Ag[2 * a]; a1 = Ag[2 * a + 1]; }
    }
    unsigned int pa = (unsigned int)f2b(a0) | ((unsigned int)f2b(a1) << 16);
    *reinterpret_cast<unsigned int*>(o + row * o_stride + 256 + h * 16 + 2 * c) = pa;
  }
}

// ---------------------------------------------------------------------------
// post self-attn
// ---------------------------------------------------------------------------
__global__ __launch_bounds__(256) void post_self_kernel(
    const float* __restrict__ xcn, const float* __restrict__ n1g,
    const float* __restrict__ n1b, float* __restrict__ out_rpos,
    float* __restrict__ xc2, unsigned short* __restrict__ h1_b) {
  int wv = threadIdx.x >> 6, lane = threadIdx.x & 63;
  int pix = blockIdx.x * 4 + wv;
  const float* row = xcn + (size_t)pix * DSELF;
  float vals[3];
#pragma unroll
  for (int i = 0; i < 3; i++) {
    int c = lane + i * 64;
    vals[i] = (c < DSELF) ? row[c] : 0.f;
  }
#pragma unroll
  for (int i = 0; i < 3; i++) {
    int c = lane + i * 64;
    if (c >= 130 && c < 146) out_rpos[(size_t)pix * 16 + (c - 130)] = vals[i];
  }
#pragma unroll
  for (int i = 0; i < 3; i++) {
    int c = lane + i * 64;
    if (c == 129) vals[i] = 0.f;
  }
  float* x2row = xc2 + (size_t)pix * DCROSS;
#pragma unroll
  for (int i = 0; i < 3; i++) {
    int c = lane + i * 64;
    if (c < DCROSS) x2row[c] = vals[i];
  }
  float s = 0.f;
#pragma unroll
  for (int i = 0; i < 3; i++) { int c = lane + i * 64; if (c < DCROSS) s += vals[i]; }
  float mu = wave_bcast_sum(s) * (1.f / DCROSS);
  float s2 = 0.f;
#pragma unroll
  for (int i = 0; i < 3; i++) {
    int c = lane + i * 64;
    if (c < DCROSS) { float d = vals[i] - mu; s2 += d * d; }
  }
  float var = wave_bcast_sum(s2) * (1.f / DCROSS);
  float rs = rsqrtf(var + 1e-5f);
  unsigned short* h1row = h1_b + (size_t)pix * 160;
#pragma unroll
  for (int i = 0; i < 3; i++) {
    int c = lane + i * 64;
    if (c < 160) {
      float v = (c < DCROSS) ? (vals[i] - mu) * rs * n1g[c] + n1b[c] : 0.f;
      h1row[c] = f2b(v);
    }
  }
}

// ---------------------------------------------------------------------------
// post cross-attn
// ---------------------------------------------------------------------------
__global__ __launch_bounds__(256) void post_cross_kernel(
    const float* __restrict__ xc2n, const float* __restrict__ fs,
    const float* __restrict__ n2g, const float* __restrict__ n2b,
    float* __restrict__ out_f2, float* __restrict__ xob,
    unsigned short* __restrict__ h2_b) {
  int wv = threadIdx.x >> 6, lane = threadIdx.x & 63;
  int pix = blockIdx.x * 4 + wv;
  const float* row = xc2n + (size_t)pix * DCROSS;
  float vals[3];
#pragma unroll
  for (int i = 0; i < 3; i++) {
    int c = lane + i * 64;
    vals[i] = (c < DCROSS) ? row[c] : 0.f;
  }
  if (lane == 0) out_f2[(size_t)pix * 2 + 0] = vals[2] / fs[0];
  if (lane == 1) out_f2[(size_t)pix * 2 + 1] = 0.f;
  float* xrow = xob + (size_t)pix * Cch;
#pragma unroll
  for (int i = 0; i < 2; i++) {
    int c = lane + i * 64;
    xrow[c] = vals[i];
  }
  float s = vals[0] + vals[1];
  float mu = wave_bcast_sum(s) * (1.f / Cch);
  float d0 = vals[0] - mu, d1 = vals[1] - mu;
  float var = wave_bcast_sum(d0 * d0 + d1 * d1) * (1.f / Cch);
  float rs = rsqrtf(var + 1e-5f);
  unsigned short* h2row = h2_b + (size_t)pix * Cch;
#pragma unroll
  for (int i = 0; i < 2; i++) {
    int c = lane + i * 64;
    h2row[c] = f2b((vals[i] - mu) * rs * n2g[c] + n2b[c]);
  }
}

// depthwise 3x3 SAME + bias, exact gelu, * gate -> bf16
__global__ __launch_bounds__(256) void dwconv_kernel(
    const float* __restrict__ u, const float* __restrict__ dww,
    const float* __restrict__ dwb, unsigned short* __restrict__ aout) {
  int t = blockIdx.x * 256 + threadIdx.x;
  int c = t & 255;
  int pix = t >> 8;
  int b = pix / Nn, n = pix - b * Nn;
  int py = n / Ww, px = n - py * Ww;
  float acc = dwb[c];
#pragma unroll
  for (int ky = 0; ky < 3; ky++) {
    int yy = py + ky - 1;
    if (yy < 0 || yy >= Hh) continue;
#pragma unroll
    for (int kx = 0; kx < 3; kx++) {
      int xx = px + kx - 1;
      if (xx < 0 || xx >= Ww) continue;
      acc += u[((size_t)(b * Nn + yy * Ww + xx)) * 512 + c] * dww[(ky * 3 + kx) * 256 + c];
    }
  }
  float ge = 0.5f * acc * (1.f + erff(acc * 0.70710678118654752f));
  aout[(size_t)pix * 256 + c] = f2b(ge * u[(size_t)pix * 512 + 256 + c]);
}

extern "C" void kernel_launch(void* const* d_in, const int* in_sizes, int n_in,
                              void* d_out, int out_size, void* d_ws, size_t ws_size,
                              hipStream_t stream) {
  (void)in_sizes; (void)n_in; (void)out_size; (void)ws_size;
  const float* x    = (const float*)d_in[0];
  const float* rpos = (const float*)d_in[1];
  const float* field= (const float*)d_in[2];
  const float* fs   = (const float*)d_in[3];
  const float* n0g  = (const float*)d_in[4];
  const float* n0b  = (const float*)d_in[5];
  const float* n1g  = (const float*)d_in[6];
  const float* n1b  = (const float*)d_in[7];
  const float* n2g  = (const float*)d_in[8];
  const float* n2b  = (const float*)d_in[9];
  const float* sq_w = (const float*)d_in[10];
  const float* sk_w = (const float*)d_in[11];
  const float* sv_w = (const float*)d_in[12];
  const float* sp_w = (const float*)d_in[13];
  const float* cq_w = (const float*)d_in[14];
  const float* ck_w = (const float*)d_in[15];
  const float* cv_w = (const float*)d_in[16];
  const float* cg_w = (const float*)d_in[17];
  const float* cp_w = (const float*)d_in[18];
  const float* fc1w = (const float*)d_in[19];
  const float* fc1b = (const float*)d_in[20];
  const float* dww  = (const float*)d_in[21];
  const float* dwb  = (const float*)d_in[22];
  const float* fc2w = (const float*)d_in[23];
  const float* fc2b = (const float*)d_in[24];

  float* ws = (float*)d_ws;
  float* xc   = ws + 0;
  float* xcn  = ws + 1345536;
  float* q    = ws + 2691072;
  float* k    = ws + 5050368;
  float* v    = ws + 7409664;
  float* g    = ws + 9768960;
  float* xc2  = ws + 12128256;
  float* xob  = ws + 13326336;
  unsigned short* xe_b   = (unsigned short*)(ws + 14505984);
  unsigned short* o_b    = (unsigned short*)(ws + 15243264);
  unsigned short* h1_b   = (unsigned short*)(ws + 16422912);
  unsigned short* ocat_b = (unsigned short*)(ws + 17160192);
  unsigned short* h2_b   = (unsigned short*)(ws + 18929664);
  unsigned short* warena = (unsigned short*)(ws + 19519488);
  float* u    = q;
  float* xc2n = v;
  unsigned short* aconv_b = o_b;

  float* out_xo   = (float*)d_out;
  float* out_rpos = out_xo + 1179648;
  float* out_f2   = out_xo + 1327104;

  const int oSQ = 0, oSK = 40960, oSV = 81920, oSP = 122880, oCQ = 160256,
            oCK = 201216, oCV = 242176, oCG = 283136, oCP = 324096,
            oF1 = 374016, oF2 = 439552;
  WPack wp;
  auto setw = [&](int i, const float* src, int K, int N, int Kp, int off) {
    wp.d[i].src = src; wp.d[i].K = K; wp.d[i].N = N; wp.d[i].Kp = Kp;
    wp.d[i].dstOff = off;
  };
  setw(0, sq_w, 147, 256, 160, oSQ);
  setw(1, sk_w, 147, 256, 160, oSK);
  setw(2, sv_w, 147, 256, 160, oSV);
  setw(3, sp_w, 256, 146, 256, oSP);
  setw(4, cq_w, 130, 256, 160, oCQ);
  setw(5, ck_w, 130, 256, 160, oCK);
  setw(6, cv_w, 130, 256, 160, oCV);
  setw(7, cg_w, 130, 256, 160, oCG);
  setw(8, cp_w, 384, 130, 384, oCP);
  setw(9, fc1w, 128, 512, 128, oF1);
  setw(10, fc2w, 256, 128, 256, oF2);
  int nblk = 0;
  for (int i = 0; i < 11; i++) {
    wp.d[i].blkOff = nblk;
    nblk += (wp.d[i].N * wp.d[i].Kp + 2047) / 2048;
  }

  dim3 blk(256);
  auto gemm = [&](const unsigned short* A, int Kp, int woff, int N,
                  const float* bias, const float* resid, float* out,
                  int swapA, int act) {
    dim3 grid((N + 63) / 64, Mrows / 64);
    mfma_gemm_kernel<<<grid, blk, 0, stream>>>(A, Kp, warena + woff, N, bias,
                                               resid, out, swapA, act);
  };

  convert_w_kernel<<<nblk, blk, 0, stream>>>(wp, warena);
  prep_kernel<<<2304, blk, 0, stream>>>(x, rpos, field, fs, n0g, n0b, xc, xe_b);
  gemm(xe_b, 160, oSQ, 256, nullptr, nullptr, q, 0, 0);
  gemm(xe_b, 160, oSK, 256, nullptr, nullptr, k, 0, 0);
  gemm(xe_b, 160, oSV, 256, nullptr, nullptr, v, 0, 0);
  attn_wave_kernel<<<2304, blk, 0, stream>>>(q, k, v, rpos, nullptr, fs, nullptr,
                                             o_b, 256, 0);
  gemm(o_b, 256, oSP, 146, nullptr, xc, xcn, 0, 0);
  post_self_kernel<<<2304, blk, 0, stream>>>(xcn, n1g, n1b, out_rpos, xc2, h1_b);
  gemm(h1_b, 160, oCQ, 256, nullptr, nullptr, q, 0, 0);
  gemm(h1_b, 160, oCK, 256, nullptr, nullptr, k, 1, 0);
  gemm(h1_b, 160, oCV, 256, nullptr, nullptr, v, 1, 0);
  gemm(h1_b, 160, oCG, 256, nullptr, nullptr, g, 0, 1);
  attn_wave_kernel<<<2304, blk, 0, stream>>>(q, k, v, nullptr, xc2, fs, g,
                                             ocat_b, 384, 1);
  gemm(ocat_b, 384, oCP, 130, nullptr, xc2, xc2n, 0, 0);
  post_cross_kernel<<<2304, blk, 0, stream>>>(xc2n, fs, n2g, n2b, out_f2, xob, h2_b);
  gemm(h2_b, 128, oF1, 512, fc1b, nullptr, u, 0, 0);
  dwconv_kernel<<<9216, blk, 0, stream>>>(u, dww, dwb, aconv_b);
  gemm(aconv_b, 256, oF2, 128, fc2b, xob, out_xo, 0, 0);
}

// Round 6
// 161.877 us; speedup vs baseline: 3.5670x; 1.1292x over previous
//
#include <hip/hip_runtime.h>
#include <math.h>

namespace {
constexpr int Bn = 2, Hh = 48, Ww = 96, Cch = 128;
constexpr int Nn = Hh * Ww;            // 4608
constexpr int NHh = 8;
constexpr int DSELF = 146, ESELF = 147, DCROSS = 130;
constexpr int Mrows = Bn * Nn;         // 9216
constexpr float SCALEf = 0.17677669529663687f; // 32^-0.5
}

typedef float f32x4 __attribute__((ext_vector_type(4)));
typedef short s16x8 __attribute__((ext_vector_type(8)));

__device__ __forceinline__ unsigned short f2b(float f) {
  unsigned int u = __float_as_uint(f);
  u = u + 0x7fffu + ((u >> 16) & 1u);
  return (unsigned short)(u >> 16);
}
__device__ __forceinline__ float b2f(unsigned short u) {
  return __uint_as_float((unsigned int)u << 16);
}

__device__ __forceinline__ f32x4 mfma_bf16(s16x8 a, s16x8 b, f32x4 c) {
  f32x4 d;
  asm volatile("v_mfma_f32_16x16x32_bf16 %0, %1, %2, %3"
               : "=&v"(d) : "v"(a), "v"(b), "v"(c));
  return d;
}

__device__ __forceinline__ float wave_bcast_sum(float v) {
#pragma unroll
  for (int off = 32; off > 0; off >>= 1) v += __shfl_down(v, off);
  return __shfl(v, 0);
}

// ---------------------------------------------------------------------------
// weight convert: fp32 W[K][N] -> bf16 Wt[n][Kp] (transposed, K zero-padded)
// ---------------------------------------------------------------------------
struct WDesc { const float* src; int K, N, Kp, dstOff, blkOff; };
struct WPack { WDesc d[11]; };

__global__ __launch_bounds__(256) void convert_w_kernel(WPack p, unsigned short* dst) {
  int bi = blockIdx.x;
  int mi = 0;
#pragma unroll
  for (int i = 1; i < 11; i++) if (bi >= p.d[i].blkOff) mi = i;
  WDesc w = p.d[mi];
  int e = (bi - w.blkOff) * 2048 + threadIdx.x * 8;
  int total = w.N * w.Kp;
  if (e >= total) return;
  int n = e / w.Kp, k0 = e - n * w.Kp;
  s16x8 pack;
#pragma unroll
  for (int j = 0; j < 8; j++) {
    int kk = k0 + j;
    float vv = (kk < w.K) ? w.src[(size_t)kk * w.N + n] : 0.f;
    pack[j] = (short)f2b(vv);
  }
  *reinterpret_cast<s16x8*>(dst + w.dstOff + e) = pack;
}

// ---------------------------------------------------------------------------
// bf16 MFMA GEMM: out = act(A(bf16,[M][Kp]) @ Wt(bf16,[N][Kp])^T + bias + resid)
// act: 0 none, 1 silu all, 2 silu cols>=256. out_bf16: write bf16 else f32.
// 64x64 tile, BK=32, 4 waves each 32x32 (2x2 16x16x32 frags)
// ---------------------------------------------------------------------------
__global__ __launch_bounds__(256) void mfma_gemm_kernel(
    const unsigned short* __restrict__ A, int Kp,
    const unsigned short* __restrict__ Wt, int N,
    const float* __restrict__ bias, const float* __restrict__ resid,
    void* __restrict__ out, int swapA, int act, int out_bf16) {
  __shared__ unsigned short As[64 * 40];
  __shared__ unsigned short Bs[64 * 40];
  int tid = threadIdx.x;
  int m0 = blockIdx.y * 64, n0 = blockIdx.x * 64;
  int lane = tid & 63, wv = tid >> 6;
  int wr = wv >> 1, wc = wv & 1;
  int lr = lane & 15, lk = (lane >> 4) * 8;
  int sr = tid >> 2, sk8 = (tid & 3) * 8;
  int am = m0 + sr;
  if (swapA) am = (am < Mrows / 2) ? am + Mrows / 2 : am - Mrows / 2;
  const unsigned short* aptr = A + (size_t)am * Kp + sk8;
  int bn = n0 + sr;
  const unsigned short* bptr = (bn < N) ? Wt + (size_t)bn * Kp + sk8 : nullptr;
  f32x4 acc00 = {}, acc01 = {}, acc10 = {}, acc11 = {};
  for (int k0 = 0; k0 < Kp; k0 += 32) {
    s16x8 av = *reinterpret_cast<const s16x8*>(aptr + k0);
    s16x8 bv = {};
    if (bptr) bv = *reinterpret_cast<const s16x8*>(bptr + k0);
    *reinterpret_cast<s16x8*>(&As[sr * 40 + sk8]) = av;
    *reinterpret_cast<s16x8*>(&Bs[sr * 40 + sk8]) = bv;
    __syncthreads();
    s16x8 a0 = *reinterpret_cast<const s16x8*>(&As[(wr * 32 + lr) * 40 + lk]);
    s16x8 a1 = *reinterpret_cast<const s16x8*>(&As[(wr * 32 + 16 + lr) * 40 + lk]);
    s16x8 b0 = *reinterpret_cast<const s16x8*>(&Bs[(wc * 32 + lr) * 40 + lk]);
    s16x8 b1 = *reinterpret_cast<const s16x8*>(&Bs[(wc * 32 + 16 + lr) * 40 + lk]);
    acc00 = mfma_bf16(a0, b0, acc00);
    acc01 = mfma_bf16(a0, b1, acc01);
    acc10 = mfma_bf16(a1, b0, acc10);
    acc11 = mfma_bf16(a1, b1, acc11);
    __syncthreads();
  }
  int rowBase = m0 + wr * 32 + (lane >> 4) * 4;
  f32x4 accs[2][2] = {{acc00, acc01}, {acc10, acc11}};
#pragma unroll
  for (int fc = 0; fc < 2; fc++) {
    int col = n0 + wc * 32 + fc * 16 + lr;
    if (col >= N) continue;
    float bval = bias ? bias[col] : 0.f;
    bool dosilu = (act == 1) || (act == 2 && col >= 256);
#pragma unroll
    for (int fr = 0; fr < 2; fr++) {
#pragma unroll
      for (int r = 0; r < 4; r++) {
        int row = rowBase + fr * 16 + r;
        float vv = accs[fr][fc][r] + bval;
        if (resid) vv += resid[(size_t)row * N + col];
        if (dosilu) vv = vv / (1.f + expf(-vv));
        if (out_bf16)
          ((unsigned short*)out)[(size_t)row * N + col] = f2b(vv);
        else
          ((float*)out)[(size_t)row * N + col] = vv;
      }
    }
  }
}

// ---------------------------------------------------------------------------
// prep: xc = [x, field*fs, rpos] (f32); noc mask; xe_b = bf16[LN(xc), noc, 0pad]
// ---------------------------------------------------------------------------
__global__ __launch_bounds__(256) void prep_kernel(
    const float* __restrict__ x, const float* __restrict__ rpos,
    const float* __restrict__ field, const float* __restrict__ fs,
    const float* __restrict__ n0g, const float* __restrict__ n0b,
    float* __restrict__ xc, unsigned short* __restrict__ xe_b) {
  int wv = threadIdx.x >> 6, lane = threadIdx.x & 63;
  int pix = blockIdx.x * 4 + wv;
  int b = pix / Nn, n = pix - b * Nn;
  int py = n / Ww, px = n - py * Ww;
  const float* xrow = x + (size_t)pix * Cch;
  const float* rrow = rpos + (size_t)pix * 16;
  float f0 = field[(size_t)pix * 2 + 0], f1 = field[(size_t)pix * 2 + 1];
  float fsx = fs[0], fsy = fs[1];
  float vals[3];
#pragma unroll
  for (int i = 0; i < 3; i++) {
    int c = lane + i * 64;
    float v = 0.f;
    if (c < Cch) v = xrow[c];
    else if (c == 128) v = f0 * fsx;
    else if (c == 129) v = f1 * fsy;
    else if (c < DSELF) v = rrow[c - 130];
    vals[i] = v;
  }
  float* xcrow = xc + (size_t)pix * DSELF;
#pragma unroll
  for (int i = 0; i < 3; i++) {
    int c = lane + i * 64;
    if (c < DSELF) xcrow[c] = vals[i];
  }
  float s = 0.f;
#pragma unroll
  for (int i = 0; i < 3; i++) { int c = lane + i * 64; if (c < DSELF) s += vals[i]; }
  float mu = wave_bcast_sum(s) * (1.f / DSELF);
  float s2 = 0.f;
#pragma unroll
  for (int i = 0; i < 3; i++) {
    int c = lane + i * 64;
    if (c < DSELF) { float d = vals[i] - mu; s2 += d * d; }
  }
  float var = wave_bcast_sum(s2) * (1.f / DSELF);
  float rs = rsqrtf(var + 1e-5f);
  float noc = 0.f;
  if (lane == 0) {
    float ox = fminf(fmaxf(f0 + (float)px, 0.f), (float)(Ww - 1));
    float oy = fminf(fmaxf(f1 + (float)py, 0.f), (float)(Hh - 1));
    float x0f = fminf(fmaxf(floorf(ox), 0.f), (float)(Ww - 2));
    float y0f = fminf(fmaxf(floorf(oy), 0.f), (float)(Hh - 2));
    int x0 = (int)x0f, y0 = (int)y0f;
    float wx = ox - x0f, wy = oy - y0f;
    const float* fo = field + (size_t)(1 - b) * Nn * 2;
    const float* p00 = fo + ((size_t)y0 * Ww + x0) * 2;
    const float* p10 = fo + ((size_t)(y0 + 1) * Ww + x0) * 2;
    float v0 = (1.f - wy) * ((1.f - wx) * p00[0] + wx * p00[2]) +
               wy * ((1.f - wx) * p10[0] + wx * p10[2]);
    float v1 = (1.f - wy) * ((1.f - wx) * p00[1] + wx * p00[3]) +
               wy * ((1.f - wx) * p10[1] + wx * p10[3]);
    float diff = fabsf(f0 + v0) + fabsf(f1 + v1);
    noc = (diff < 2.f) ? 1.f : 0.f;
  }
  noc = __shfl(noc, 0);
  unsigned short* xerow = xe_b + (size_t)pix * 160;
#pragma unroll
  for (int i = 0; i < 3; i++) {
    int c = lane + i * 64;
    if (c < 160) {
      float v;
      if (c < DSELF) v = (vals[i] - mu) * rs * n0g[c] + n0b[c];
      else if (c == 146) v = noc;
      else v = 0.f;
      xerow[c] = f2b(v);
    }
  }
}

// ---------------------------------------------------------------------------
// windowed match attention, one WAVE per pixel; f32 q/k/v/g inputs (precision:
// field-channel path is x10-amplified twice), bf16 outputs.
// ---------------------------------------------------------------------------
__global__ __launch_bounds__(256) void attn_wave_kernel(
    const float* __restrict__ qbuf, int qstride, int gOff,
    const float* __restrict__ kvbuf, int kvstride, int koff, int voff,
    const float* __restrict__ rpos, const float* __restrict__ xc2,
    const float* __restrict__ fs, unsigned short* __restrict__ o, int o_stride,
    int mode) {
  int wv = threadIdx.x >> 6, lane = threadIdx.x & 63;
  int pix = blockIdx.x * 4 + wv;
  int b = pix / Nn, n = pix - b * Nn;
  int py = n / Ww, px = n - py * Ww;
  int h = lane >> 3, c = lane & 7;
  size_t row = (size_t)pix;
  float ox, oy;
  if (mode == 0) {
    ox = rpos[row * 16 + 2 * h] + (float)px;
    oy = rpos[row * 16 + 2 * h + 1] + (float)py;
  } else {
    ox = xc2[row * DCROSS + 128] / fs[0] + (float)px;
    oy = (float)py;
  }
  ox = fminf(fmaxf(ox, 1.0f), 93.999f);
  oy = fminf(fmaxf(oy, 1.0f), 45.999f);
  float mxf = floorf(ox), myf = floorf(oy);
  float fx = ox - mxf, fy = oy - myf;
  int mx = (int)mxf, my = (int)myf;
  int base = b * Nn;

  float4 qv = *reinterpret_cast<const float4*>(qbuf + row * qstride + lane * 4);
  float s[16];
#pragma unroll
  for (int j = 0; j < 4; j++) {
    int gy = my - 1 + j;
#pragma unroll
    for (int i = 0; i < 4; i++) {
      int gx = mx - 1 + i;
      int idx = gy * Ww + gx;
      float4 kv = *reinterpret_cast<const float4*>(
          kvbuf + (size_t)(base + idx) * kvstride + koff + lane * 4);
      float d = qv.x * kv.x + qv.y * kv.y + qv.z * kv.z + qv.w * kv.w;
      d += __shfl_xor(d, 1);
      d += __shfl_xor(d, 2);
      d += __shfl_xor(d, 4);
      s[j * 4 + i] = d * SCALEf;
    }
  }
  float w00 = (1.f - fy) * (1.f - fx), w01 = (1.f - fy) * fx;
  float w10 = fy * (1.f - fx), w11 = fy * fx;
  float sc[9];
#pragma unroll
  for (int j = 0; j < 3; j++)
#pragma unroll
    for (int i = 0; i < 3; i++)
      sc[j * 3 + i] = w00 * s[j * 4 + i] + w01 * s[j * 4 + i + 1] +
                      w10 * s[(j + 1) * 4 + i] + w11 * s[(j + 1) * 4 + i + 1];
  float mval = sc[0];
#pragma unroll
  for (int i = 1; i < 9; i++) mval = fmaxf(mval, sc[i]);
  float p[9], psum = 0.f;
#pragma unroll
  for (int i = 0; i < 9; i++) { p[i] = expf(sc[i] - mval); psum += p[i]; }
  float inv = 1.f / psum;
#pragma unroll
  for (int i = 0; i < 9; i++) p[i] *= inv;
  float Ag[16] = {};
#pragma unroll
  for (int j = 0; j < 3; j++)
#pragma unroll
    for (int i = 0; i < 3; i++) {
      float pv = p[j * 3 + i];
      Ag[j * 4 + i] += w00 * pv;
      Ag[j * 4 + i + 1] += w01 * pv;
      Ag[(j + 1) * 4 + i] += w10 * pv;
      Ag[(j + 1) * 4 + i + 1] += w11 * pv;
    }
  float4 acc = make_float4(0.f, 0.f, 0.f, 0.f);
#pragma unroll
  for (int j = 0; j < 4; j++) {
    int gy = my - 1 + j;
#pragma unroll
    for (int i = 0; i < 4; i++) {
      int gx = mx - 1 + i;
      int idx = gy * Ww + gx;
      float4 vv = *reinterpret_cast<const float4*>(
          kvbuf + (size_t)(base + idx) * kvstride + voff + lane * 4);
      float w = Ag[j * 4 + i];
      acc.x += w * vv.x; acc.y += w * vv.y; acc.z += w * vv.z; acc.w += w * vv.w;
    }
  }
  if (gOff >= 0) {
    float4 gg = *reinterpret_cast<const float4*>(qbuf + row * qstride + gOff + lane * 4);
    acc.x *= gg.x; acc.y *= gg.y; acc.z *= gg.z; acc.w *= gg.w;
  }
  unsigned int p0 = (unsigned int)f2b(acc.x) | ((unsigned int)f2b(acc.y) << 16);
  unsigned int p1 = (unsigned int)f2b(acc.z) | ((unsigned int)f2b(acc.w) << 16);
  *reinterpret_cast<uint2*>(o + row * o_stride + lane * 4) = make_uint2(p0, p1);
  if (mode == 1) {
    float a0 = 0.f, a1 = 0.f;
#pragma unroll
    for (int a = 0; a < 8; a++) {
      if (c == a) { a0 = Ag[2 * a]; a1 = Ag[2 * a + 1]; }
    }
    unsigned int pa = (unsigned int)f2b(a0) | ((unsigned int)f2b(a1) << 16);
    *reinterpret_cast<unsigned int*>(o + row * o_stride + 256 + h * 16 + 2 * c) = pa;
  }
}

// ---------------------------------------------------------------------------
// post self-attn
// ---------------------------------------------------------------------------
__global__ __launch_bounds__(256) void post_self_kernel(
    const float* __restrict__ xcn, const float* __restrict__ n1g,
    const float* __restrict__ n1b, float* __restrict__ out_rpos,
    float* __restrict__ xc2, unsigned short* __restrict__ h1_b) {
  int wv = threadIdx.x >> 6, lane = threadIdx.x & 63;
  int pix = blockIdx.x * 4 + wv;
  const float* row = xcn + (size_t)pix * DSELF;
  float vals[3];
#pragma unroll
  for (int i = 0; i < 3; i++) {
    int c = lane + i * 64;
    vals[i] = (c < DSELF) ? row[c] : 0.f;
  }
#pragma unroll
  for (int i = 0; i < 3; i++) {
    int c = lane + i * 64;
    if (c >= 130 && c < 146) out_rpos[(size_t)pix * 16 + (c - 130)] = vals[i];
  }
#pragma unroll
  for (int i = 0; i < 3; i++) {
    int c = lane + i * 64;
    if (c == 129) vals[i] = 0.f;
  }
  float* x2row = xc2 + (size_t)pix * DCROSS;
#pragma unroll
  for (int i = 0; i < 3; i++) {
    int c = lane + i * 64;
    if (c < DCROSS) x2row[c] = vals[i];
  }
  float s = 0.f;
#pragma unroll
  for (int i = 0; i < 3; i++) { int c = lane + i * 64; if (c < DCROSS) s += vals[i]; }
  float mu = wave_bcast_sum(s) * (1.f / DCROSS);
  float s2 = 0.f;
#pragma unroll
  for (int i = 0; i < 3; i++) {
    int c = lane + i * 64;
    if (c < DCROSS) { float d = vals[i] - mu; s2 += d * d; }
  }
  float var = wave_bcast_sum(s2) * (1.f / DCROSS);
  float rs = rsqrtf(var + 1e-5f);
  unsigned short* h1row = h1_b + (size_t)pix * 160;
#pragma unroll
  for (int i = 0; i < 3; i++) {
    int c = lane + i * 64;
    if (c < 160) {
      float v = (c < DCROSS) ? (vals[i] - mu) * rs * n1g[c] + n1b[c] : 0.f;
      h1row[c] = f2b(v);
    }
  }
}

// ---------------------------------------------------------------------------
// post cross-attn
// ---------------------------------------------------------------------------
__global__ __launch_bounds__(256) void post_cross_kernel(
    const float* __restrict__ xc2n, const float* __restrict__ fs,
    const float* __restrict__ n2g, const float* __restrict__ n2b,
    float* __restrict__ out_f2, float* __restrict__ xob,
    unsigned short* __restrict__ h2_b) {
  int wv = threadIdx.x >> 6, lane = threadIdx.x & 63;
  int pix = blockIdx.x * 4 + wv;
  const float* row = xc2n + (size_t)pix * DCROSS;
  float vals[3];
#pragma unroll
  for (int i = 0; i < 3; i++) {
    int c = lane + i * 64;
    vals[i] = (c < DCROSS) ? row[c] : 0.f;
  }
  if (lane == 0) out_f2[(size_t)pix * 2 + 0] = vals[2] / fs[0];
  if (lane == 1) out_f2[(size_t)pix * 2 + 1] = 0.f;
  float* xrow = xob + (size_t)pix * Cch;
#pragma unroll
  for (int i = 0; i < 2; i++) {
    int c = lane + i * 64;
    xrow[c] = vals[i];
  }
  float s = vals[0] + vals[1];
  float mu = wave_bcast_sum(s) * (1.f / Cch);
  float d0 = vals[0] - mu, d1 = vals[1] - mu;
  float var = wave_bcast_sum(d0 * d0 + d1 * d1) * (1.f / Cch);
  float rs = rsqrtf(var + 1e-5f);
  unsigned short* h2row = h2_b + (size_t)pix * Cch;
#pragma unroll
  for (int i = 0; i < 2; i++) {
    int c = lane + i * 64;
    h2row[c] = f2b((vals[i] - mu) * rs * n2g[c] + n2b[c]);
  }
}

// ---------------------------------------------------------------------------
// depthwise 3x3 SAME on u_b[:, :256] (bf16), + bias, exact gelu, * gate -> bf16
// 8 channels per thread (16B loads), 32 threads/pixel
// ---------------------------------------------------------------------------
__global__ __launch_bounds__(256) void dwconv_kernel(
    const unsigned short* __restrict__ ub, const float* __restrict__ dww,
    const float* __restrict__ dwb, unsigned short* __restrict__ aout) {
  int t = blockIdx.x * 256 + threadIdx.x;
  int c8 = (t & 31) * 8;
  int pix = t >> 5;
  int b = pix / Nn, n = pix - b * Nn;
  int py = n / Ww, px = n - py * Ww;
  float acc[8];
#pragma unroll
  for (int j = 0; j < 8; j++) acc[j] = dwb[c8 + j];
#pragma unroll
  for (int ky = 0; ky < 3; ky++) {
    int yy = py + ky - 1;
    if (yy < 0 || yy >= Hh) continue;
#pragma unroll
    for (int kx = 0; kx < 3; kx++) {
      int xx = px + kx - 1;
      if (xx < 0 || xx >= Ww) continue;
      s16x8 uv = *reinterpret_cast<const s16x8*>(
          ub + ((size_t)(b * Nn + yy * Ww + xx)) * 512 + c8);
      const float* wrow = dww + (ky * 3 + kx) * 256 + c8;
#pragma unroll
      for (int j = 0; j < 8; j++)
        acc[j] += b2f((unsigned short)uv[j]) * wrow[j];
    }
  }
  s16x8 gate = *reinterpret_cast<const s16x8*>(ub + (size_t)pix * 512 + 256 + c8);
  s16x8 outp;
#pragma unroll
  for (int j = 0; j < 8; j++) {
    float a = acc[j];
    float ge = 0.5f * a * (1.f + erff(a * 0.70710678118654752f));
    outp[j] = (short)f2b(ge * b2f((unsigned short)gate[j]));
  }
  *reinterpret_cast<s16x8*>(aout + (size_t)pix * 256 + c8) = outp;
}

extern "C" void kernel_launch(void* const* d_in, const int* in_sizes, int n_in,
                              void* d_out, int out_size, void* d_ws, size_t ws_size,
                              hipStream_t stream) {
  (void)in_sizes; (void)n_in; (void)out_size; (void)ws_size;
  const float* x    = (const float*)d_in[0];
  const float* rpos = (const float*)d_in[1];
  const float* field= (const float*)d_in[2];
  const float* fs   = (const float*)d_in[3];
  const float* n0g  = (const float*)d_in[4];
  const float* n0b  = (const float*)d_in[5];
  const float* n1g  = (const float*)d_in[6];
  const float* n1b  = (const float*)d_in[7];
  const float* n2g  = (const float*)d_in[8];
  const float* n2b  = (const float*)d_in[9];
  const float* sq_w = (const float*)d_in[10];
  const float* sk_w = (const float*)d_in[11];
  const float* sv_w = (const float*)d_in[12];
  const float* sp_w = (const float*)d_in[13];
  const float* cq_w = (const float*)d_in[14];
  const float* ck_w = (const float*)d_in[15];
  const float* cv_w = (const float*)d_in[16];
  const float* cg_w = (const float*)d_in[17];
  const float* cp_w = (const float*)d_in[18];
  const float* fc1w = (const float*)d_in[19];
  const float* fc1b = (const float*)d_in[20];
  const float* dww  = (const float*)d_in[21];
  const float* dwb  = (const float*)d_in[22];
  const float* fc2w = (const float*)d_in[23];
  const float* fc2b = (const float*)d_in[24];

  float* ws = (float*)d_ws;
  // layout (float offsets); total ~28.0M floats = 112 MB (ws >= 268 MB)
  float* xc    = ws + 0;         // 1345536
  float* xcn   = ws + 1345536;   // 1345536
  float* xc2   = ws + 2691072;   // 1198080
  float* xc2n  = ws + 3889152;   // 1198080
  float* xob   = ws + 5087232;   // 1179648
  unsigned short* xe_b   = (unsigned short*)(ws + 6266880);   // 737280 f
  unsigned short* h1_b   = (unsigned short*)(ws + 7004160);   // 737280 f
  unsigned short* h2_b   = (unsigned short*)(ws + 7741440);   // 589824 f
  float* qkv   = ws + 8331264;   // 9216*768 f32 = 7077888 f
  float* qg    = ws + 15409152;  // 9216*512 f32 = 4718592 f
  float* kv    = ws + 20127744;  // 9216*512 f32 = 4718592 f
  unsigned short* o_b    = (unsigned short*)(ws + 24846336);  // 9216*256 -> 1179648 f
  unsigned short* ocat_b = (unsigned short*)(ws + 26025984);  // 9216*384 -> 1769472 f
  unsigned short* warena = (unsigned short*)(ws + 27795456);  // 472320 us -> 236160 f
  unsigned short* u_b    = (unsigned short*)qkv;  // qkv dead after self-attn
  unsigned short* aconv_b = o_b;                  // o_b dead after sp GEMM

  float* out_xo   = (float*)d_out;
  float* out_rpos = out_xo + 1179648;
  float* out_f2   = out_xo + 1327104;

  // arena layout (ushort offsets): fused groups contiguous in n
  const int oSQKV = 0;                       // sq|sk|sv: 768 rows * 160
  const int oSP   = 122880;                  // 146 * 256
  const int oCQG  = 160256;                  // cq|cg: 512 rows * 160
  const int oCKV  = 242176;                  // ck|cv: 512 rows * 160
  const int oCP   = 324096;                  // 130 * 384
  const int oF1   = 374016;                  // 512 * 128
  const int oF2   = 439552;                  // 128 * 256 (ends 472320)
  WPack wp;
  auto setw = [&](int i, const float* src, int K, int N, int Kp, int off) {
    wp.d[i].src = src; wp.d[i].K = K; wp.d[i].N = N; wp.d[i].Kp = Kp;
    wp.d[i].dstOff = off;
  };
  setw(0, sq_w, 147, 256, 160, oSQKV);
  setw(1, sk_w, 147, 256, 160, oSQKV + 40960);
  setw(2, sv_w, 147, 256, 160, oSQKV + 81920);
  setw(3, sp_w, 256, 146, 256, oSP);
  setw(4, cq_w, 130, 256, 160, oCQG);
  setw(5, cg_w, 130, 256, 160, oCQG + 40960);
  setw(6, ck_w, 130, 256, 160, oCKV);
  setw(7, cv_w, 130, 256, 160, oCKV + 40960);
  setw(8, cp_w, 384, 130, 384, oCP);
  setw(9, fc1w, 128, 512, 128, oF1);
  setw(10, fc2w, 256, 128, 256, oF2);
  int nblk = 0;
  for (int i = 0; i < 11; i++) {
    wp.d[i].blkOff = nblk;
    nblk += (wp.d[i].N * wp.d[i].Kp + 2047) / 2048;
  }

  dim3 blk(256);
  auto gemm = [&](const unsigned short* A, int Kp, int woff, int N,
                  const float* bias, const float* resid, void* out,
                  int swapA, int act, int obf) {
    dim3 grid((N + 63) / 64, Mrows / 64);
    mfma_gemm_kernel<<<grid, blk, 0, stream>>>(A, Kp, warena + woff, N, bias,
                                               resid, out, swapA, act, obf);
  };

  convert_w_kernel<<<nblk, blk, 0, stream>>>(wp, warena);
  prep_kernel<<<2304, blk, 0, stream>>>(x, rpos, field, fs, n0g, n0b, xc, xe_b);
  // fused QKV (self): N=768 -> qkv f32
  gemm(xe_b, 160, oSQKV, 768, nullptr, nullptr, qkv, 0, 0, 0);
  attn_wave_kernel<<<2304, blk, 0, stream>>>(qkv, 768, -1, qkv, 768, 256, 512,
                                             rpos, nullptr, fs, o_b, 256, 0);
  gemm(o_b, 256, oSP, 146, nullptr, xc, xcn, 0, 0, 0);
  post_self_kernel<<<2304, blk, 0, stream>>>(xcn, n1g, n1b, out_rpos, xc2, h1_b);
  // fused cq|cg (no swap, silu on cols>=256) and ck|cv (swapped) -> f32
  gemm(h1_b, 160, oCQG, 512, nullptr, nullptr, qg, 0, 2, 0);
  gemm(h1_b, 160, oCKV, 512, nullptr, nullptr, kv, 1, 0, 0);
  attn_wave_kernel<<<2304, blk, 0, stream>>>(qg, 512, 256, kv, 512, 0, 256,
                                             nullptr, xc2, fs, ocat_b, 384, 1);
  gemm(ocat_b, 384, oCP, 130, nullptr, xc2, xc2n, 0, 0, 0);
  post_cross_kernel<<<2304, blk, 0, stream>>>(xc2n, fs, n2g, n2b, out_f2, xob, h2_b);
  gemm(h2_b, 128, oF1, 512, fc1b, nullptr, u_b, 0, 0, 1);
  dwconv_kernel<<<1152, blk, 0, stream>>>(u_b, dww, dwb, aconv_b);
  gemm(aconv_b, 256, oF2, 128, fc2b, xob, out_xo, 0, 0, 0);
}

// Round 7
// 160.882 us; speedup vs baseline: 3.5891x; 1.0062x over previous
//
#include <hip/hip_runtime.h>
#include <math.h>

namespace {
constexpr int Bn = 2, Hh = 48, Ww = 96, Cch = 128;
constexpr int Nn = Hh * Ww;            // 4608
constexpr int NHh = 8;
constexpr int DSELF = 146, ESELF = 147, DCROSS = 130;
constexpr int Mrows = Bn * Nn;         // 9216
constexpr float SCALEf = 0.17677669529663687f; // 32^-0.5
}

typedef float f32x4 __attribute__((ext_vector_type(4)));
typedef short s16x8 __attribute__((ext_vector_type(8)));

__device__ __forceinline__ unsigned short f2b(float f) {
  unsigned int u = __float_as_uint(f);
  u = u + 0x7fffu + ((u >> 16) & 1u);
  return (unsigned short)(u >> 16);
}
__device__ __forceinline__ float b2f(unsigned short u) {
  return __uint_as_float((unsigned int)u << 16);
}

__device__ __forceinline__ f32x4 mfma_bf16(s16x8 a, s16x8 b, f32x4 c) {
  f32x4 d;
  asm volatile("v_mfma_f32_16x16x32_bf16 %0, %1, %2, %3"
               : "=&v"(d) : "v"(a), "v"(b), "v"(c));
  return d;
}

__device__ __forceinline__ float wave_bcast_sum(float v) {
#pragma unroll
  for (int off = 32; off > 0; off >>= 1) v += __shfl_down(v, off);
  return __shfl(v, 0);
}

// ---------------------------------------------------------------------------
// weight descs for fused convert (runs inside prep launch)
// ---------------------------------------------------------------------------
struct WDesc { const float* src; int K, N, Kp, dstOff, blkOff; };
struct WPack { WDesc d[11]; };

__device__ __forceinline__ void convert_w_body(const WPack& p, unsigned short* dst,
                                               int bi) {
  int mi = 0;
#pragma unroll
  for (int i = 1; i < 11; i++) if (bi >= p.d[i].blkOff) mi = i;
  WDesc w = p.d[mi];
  int e = (bi - w.blkOff) * 2048 + threadIdx.x * 8;
  int total = w.N * w.Kp;
  if (e >= total) return;
  int n = e / w.Kp, k0 = e - n * w.Kp;
  s16x8 pack;
#pragma unroll
  for (int j = 0; j < 8; j++) {
    int kk = k0 + j;
    float vv = (kk < w.K) ? w.src[(size_t)kk * w.N + n] : 0.f;
    pack[j] = (short)f2b(vv);
  }
  *reinterpret_cast<s16x8*>(dst + w.dstOff + e) = pack;
}

// ---------------------------------------------------------------------------
// bf16 MFMA GEMM, 64x64 tile, 256 thr (4 waves x 32x32), BK=32
// ---------------------------------------------------------------------------
__global__ __launch_bounds__(256) void mfma_gemm_kernel(
    const unsigned short* __restrict__ A, int Kp,
    const unsigned short* __restrict__ Wt, int N,
    const float* __restrict__ bias, const float* __restrict__ resid,
    void* __restrict__ out, int swapA, int act, int out_bf16) {
  __shared__ unsigned short As[64 * 40];
  __shared__ unsigned short Bs[64 * 40];
  int tid = threadIdx.x;
  int m0 = blockIdx.y * 64, n0 = blockIdx.x * 64;
  int lane = tid & 63, wv = tid >> 6;
  int wr = wv >> 1, wc = wv & 1;
  int lr = lane & 15, lk = (lane >> 4) * 8;
  int sr = tid >> 2, sk8 = (tid & 3) * 8;
  int am = m0 + sr;
  if (swapA) am = (am < Mrows / 2) ? am + Mrows / 2 : am - Mrows / 2;
  const unsigned short* aptr = A + (size_t)am * Kp + sk8;
  int bn = n0 + sr;
  const unsigned short* bptr = (bn < N) ? Wt + (size_t)bn * Kp + sk8 : nullptr;
  f32x4 acc00 = {}, acc01 = {}, acc10 = {}, acc11 = {};
  for (int k0 = 0; k0 < Kp; k0 += 32) {
    s16x8 av = *reinterpret_cast<const s16x8*>(aptr + k0);
    s16x8 bv = {};
    if (bptr) bv = *reinterpret_cast<const s16x8*>(bptr + k0);
    *reinterpret_cast<s16x8*>(&As[sr * 40 + sk8]) = av;
    *reinterpret_cast<s16x8*>(&Bs[sr * 40 + sk8]) = bv;
    __syncthreads();
    s16x8 a0 = *reinterpret_cast<const s16x8*>(&As[(wr * 32 + lr) * 40 + lk]);
    s16x8 a1 = *reinterpret_cast<const s16x8*>(&As[(wr * 32 + 16 + lr) * 40 + lk]);
    s16x8 b0 = *reinterpret_cast<const s16x8*>(&Bs[(wc * 32 + lr) * 40 + lk]);
    s16x8 b1 = *reinterpret_cast<const s16x8*>(&Bs[(wc * 32 + 16 + lr) * 40 + lk]);
    acc00 = mfma_bf16(a0, b0, acc00);
    acc01 = mfma_bf16(a0, b1, acc01);
    acc10 = mfma_bf16(a1, b0, acc10);
    acc11 = mfma_bf16(a1, b1, acc11);
    __syncthreads();
  }
  int rowBase = m0 + wr * 32 + (lane >> 4) * 4;
  f32x4 accs[2][2] = {{acc00, acc01}, {acc10, acc11}};
#pragma unroll
  for (int fc = 0; fc < 2; fc++) {
    int col = n0 + wc * 32 + fc * 16 + lr;
    if (col >= N) continue;
    float bval = bias ? bias[col] : 0.f;
    bool dosilu = (act == 1) || (act == 2 && col >= 256);
#pragma unroll
    for (int fr = 0; fr < 2; fr++) {
#pragma unroll
      for (int r = 0; r < 4; r++) {
        int row = rowBase + fr * 16 + r;
        float vv = accs[fr][fc][r] + bval;
        if (resid) vv += resid[(size_t)row * N + col];
        if (dosilu) vv = vv / (1.f + expf(-vv));
        if (out_bf16)
          ((unsigned short*)out)[(size_t)row * N + col] = f2b(vv);
        else
          ((float*)out)[(size_t)row * N + col] = vv;
      }
    }
  }
}

// ---------------------------------------------------------------------------
// bf16 MFMA GEMM, 32x64 tile, 128 thr (2 waves x 32x32), BK=32 — for small N
// (doubles grid for latency-bound small-N GEMMs)
// ---------------------------------------------------------------------------
__global__ __launch_bounds__(128) void mfma_gemm32_kernel(
    const unsigned short* __restrict__ A, int Kp,
    const unsigned short* __restrict__ Wt, int N,
    const float* __restrict__ bias, const float* __restrict__ resid,
    void* __restrict__ out, int swapA, int act, int out_bf16) {
  __shared__ unsigned short As[32 * 40];
  __shared__ unsigned short Bs[64 * 40];
  int tid = threadIdx.x;             // 0..127
  int m0 = blockIdx.y * 32, n0 = blockIdx.x * 64;
  int lane = tid & 63, wv = tid >> 6;  // wave -> col half
  int lr = lane & 15, lk = (lane >> 4) * 8;
  int sr = tid >> 2, sk8 = (tid & 3) * 8;  // sr 0..31
  int am = m0 + sr;
  if (swapA) am = (am < Mrows / 2) ? am + Mrows / 2 : am - Mrows / 2;
  const unsigned short* aptr = A + (size_t)am * Kp + sk8;
  int bn0 = n0 + sr, bn1 = n0 + sr + 32;
  const unsigned short* bptr0 = (bn0 < N) ? Wt + (size_t)bn0 * Kp + sk8 : nullptr;
  const unsigned short* bptr1 = (bn1 < N) ? Wt + (size_t)bn1 * Kp + sk8 : nullptr;
  f32x4 acc00 = {}, acc01 = {}, acc10 = {}, acc11 = {};
  for (int k0 = 0; k0 < Kp; k0 += 32) {
    s16x8 av = *reinterpret_cast<const s16x8*>(aptr + k0);
    s16x8 bv0 = {}, bv1 = {};
    if (bptr0) bv0 = *reinterpret_cast<const s16x8*>(bptr0 + k0);
    if (bptr1) bv1 = *reinterpret_cast<const s16x8*>(bptr1 + k0);
    *reinterpret_cast<s16x8*>(&As[sr * 40 + sk8]) = av;
    *reinterpret_cast<s16x8*>(&Bs[sr * 40 + sk8]) = bv0;
    *reinterpret_cast<s16x8*>(&Bs[(sr + 32) * 40 + sk8]) = bv1;
    __syncthreads();
    s16x8 a0 = *reinterpret_cast<const s16x8*>(&As[lr * 40 + lk]);
    s16x8 a1 = *reinterpret_cast<const s16x8*>(&As[(16 + lr) * 40 + lk]);
    s16x8 b0 = *reinterpret_cast<const s16x8*>(&Bs[(wv * 32 + lr) * 40 + lk]);
    s16x8 b1 = *reinterpret_cast<const s16x8*>(&Bs[(wv * 32 + 16 + lr) * 40 + lk]);
    acc00 = mfma_bf16(a0, b0, acc00);
    acc01 = mfma_bf16(a0, b1, acc01);
    acc10 = mfma_bf16(a1, b0, acc10);
    acc11 = mfma_bf16(a1, b1, acc11);
    __syncthreads();
  }
  int rowBase = m0 + (lane >> 4) * 4;
  f32x4 accs[2][2] = {{acc00, acc01}, {acc10, acc11}};
#pragma unroll
  for (int fc = 0; fc < 2; fc++) {
    int col = n0 + wv * 32 + fc * 16 + lr;
    if (col >= N) continue;
    float bval = bias ? bias[col] : 0.f;
    bool dosilu = (act == 1) || (act == 2 && col >= 256);
#pragma unroll
    for (int fr = 0; fr < 2; fr++) {
#pragma unroll
      for (int r = 0; r < 4; r++) {
        int row = rowBase + fr * 16 + r;
        float vv = accs[fr][fc][r] + bval;
        if (resid) vv += resid[(size_t)row * N + col];
        if (dosilu) vv = vv / (1.f + expf(-vv));
        if (out_bf16)
          ((unsigned short*)out)[(size_t)row * N + col] = f2b(vv);
        else
          ((float*)out)[(size_t)row * N + col] = vv;
      }
    }
  }
}

// ---------------------------------------------------------------------------
// prep (+ fused weight convert in first nconv blocks):
// xc = [x, field*fs, rpos] (f32); noc mask; xe_b = bf16[LN(xc), noc, 0pad]
// ---------------------------------------------------------------------------
__global__ __launch_bounds__(256) void prep_kernel(
    WPack wp, unsigned short* __restrict__ warena, int nconv,
    const float* __restrict__ x, const float* __restrict__ rpos,
    const float* __restrict__ field, const float* __restrict__ fs,
    const float* __restrict__ n0g, const float* __restrict__ n0b,
    float* __restrict__ xc, unsigned short* __restrict__ xe_b) {
  if (blockIdx.x < (unsigned)nconv) {
    convert_w_body(wp, warena, blockIdx.x);
    return;
  }
  int wv = threadIdx.x >> 6, lane = threadIdx.x & 63;
  int pix = (blockIdx.x - nconv) * 4 + wv;
  int b = pix / Nn, n = pix - b * Nn;
  int py = n / Ww, px = n - py * Ww;
  const float* xrow = x + (size_t)pix * Cch;
  const float* rrow = rpos + (size_t)pix * 16;
  float f0 = field[(size_t)pix * 2 + 0], f1 = field[(size_t)pix * 2 + 1];
  float fsx = fs[0], fsy = fs[1];
  float vals[3];
#pragma unroll
  for (int i = 0; i < 3; i++) {
    int c = lane + i * 64;
    float v = 0.f;
    if (c < Cch) v = xrow[c];
    else if (c == 128) v = f0 * fsx;
    else if (c == 129) v = f1 * fsy;
    else if (c < DSELF) v = rrow[c - 130];
    vals[i] = v;
  }
  float* xcrow = xc + (size_t)pix * DSELF;
#pragma unroll
  for (int i = 0; i < 3; i++) {
    int c = lane + i * 64;
    if (c < DSELF) xcrow[c] = vals[i];
  }
  float s = 0.f;
#pragma unroll
  for (int i = 0; i < 3; i++) { int c = lane + i * 64; if (c < DSELF) s += vals[i]; }
  float mu = wave_bcast_sum(s) * (1.f / DSELF);
  float s2 = 0.f;
#pragma unroll
  for (int i = 0; i < 3; i++) {
    int c = lane + i * 64;
    if (c < DSELF) { float d = vals[i] - mu; s2 += d * d; }
  }
  float var = wave_bcast_sum(s2) * (1.f / DSELF);
  float rs = rsqrtf(var + 1e-5f);
  float noc = 0.f;
  if (lane == 0) {
    float ox = fminf(fmaxf(f0 + (float)px, 0.f), (float)(Ww - 1));
    float oy = fminf(fmaxf(f1 + (float)py, 0.f), (float)(Hh - 1));
    float x0f = fminf(fmaxf(floorf(ox), 0.f), (float)(Ww - 2));
    float y0f = fminf(fmaxf(floorf(oy), 0.f), (float)(Hh - 2));
    int x0 = (int)x0f, y0 = (int)y0f;
    float wx = ox - x0f, wy = oy - y0f;
    const float* fo = field + (size_t)(1 - b) * Nn * 2;
    const float* p00 = fo + ((size_t)y0 * Ww + x0) * 2;
    const float* p10 = fo + ((size_t)(y0 + 1) * Ww + x0) * 2;
    float v0 = (1.f - wy) * ((1.f - wx) * p00[0] + wx * p00[2]) +
               wy * ((1.f - wx) * p10[0] + wx * p10[2]);
    float v1 = (1.f - wy) * ((1.f - wx) * p00[1] + wx * p00[3]) +
               wy * ((1.f - wx) * p10[1] + wx * p10[3]);
    float diff = fabsf(f0 + v0) + fabsf(f1 + v1);
    noc = (diff < 2.f) ? 1.f : 0.f;
  }
  noc = __shfl(noc, 0);
  unsigned short* xerow = xe_b + (size_t)pix * 160;
#pragma unroll
  for (int i = 0; i < 3; i++) {
    int c = lane + i * 64;
    if (c < 160) {
      float v;
      if (c < DSELF) v = (vals[i] - mu) * rs * n0g[c] + n0b[c];
      else if (c == 146) v = noc;
      else v = 0.f;
      xerow[c] = f2b(v);
    }
  }
}

// ---------------------------------------------------------------------------
// windowed match attention, one WAVE per pixel; f32 q/k/v/g inputs (precision:
// field-channel path is x10-amplified twice), bf16 outputs.
// ---------------------------------------------------------------------------
__global__ __launch_bounds__(256) void attn_wave_kernel(
    const float* __restrict__ qbuf, int qstride, int gOff,
    const float* __restrict__ kvbuf, int kvstride, int koff, int voff,
    const float* __restrict__ rpos, const float* __restrict__ xc2,
    const float* __restrict__ fs, unsigned short* __restrict__ o, int o_stride,
    int mode) {
  int wv = threadIdx.x >> 6, lane = threadIdx.x & 63;
  int pix = blockIdx.x * 4 + wv;
  int b = pix / Nn, n = pix - b * Nn;
  int py = n / Ww, px = n - py * Ww;
  int h = lane >> 3, c = lane & 7;
  size_t row = (size_t)pix;
  float ox, oy;
  if (mode == 0) {
    ox = rpos[row * 16 + 2 * h] + (float)px;
    oy = rpos[row * 16 + 2 * h + 1] + (float)py;
  } else {
    ox = xc2[row * DCROSS + 128] / fs[0] + (float)px;
    oy = (float)py;
  }
  ox = fminf(fmaxf(ox, 1.0f), 93.999f);
  oy = fminf(fmaxf(oy, 1.0f), 45.999f);
  float mxf = floorf(ox), myf = floorf(oy);
  float fx = ox - mxf, fy = oy - myf;
  int mx = (int)mxf, my = (int)myf;
  int base = b * Nn;

  float4 qv = *reinterpret_cast<const float4*>(qbuf + row * qstride + lane * 4);
  float s[16];
#pragma unroll
  for (int j = 0; j < 4; j++) {
    int gy = my - 1 + j;
#pragma unroll
    for (int i = 0; i < 4; i++) {
      int gx = mx - 1 + i;
      int idx = gy * Ww + gx;
      float4 kv = *reinterpret_cast<const float4*>(
          kvbuf + (size_t)(base + idx) * kvstride + koff + lane * 4);
      float d = qv.x * kv.x + qv.y * kv.y + qv.z * kv.z + qv.w * kv.w;
      d += __shfl_xor(d, 1);
      d += __shfl_xor(d, 2);
      d += __shfl_xor(d, 4);
      s[j * 4 + i] = d * SCALEf;
    }
  }
  float w00 = (1.f - fy) * (1.f - fx), w01 = (1.f - fy) * fx;
  float w10 = fy * (1.f - fx), w11 = fy * fx;
  float sc[9];
#pragma unroll
  for (int j = 0; j < 3; j++)
#pragma unroll
    for (int i = 0; i < 3; i++)
      sc[j * 3 + i] = w00 * s[j * 4 + i] + w01 * s[j * 4 + i + 1] +
                      w10 * s[(j + 1) * 4 + i] + w11 * s[(j + 1) * 4 + i + 1];
  float mval = sc[0];
#pragma unroll
  for (int i = 1; i < 9; i++) mval = fmaxf(mval, sc[i]);
  float p[9], psum = 0.f;
#pragma unroll
  for (int i = 0; i < 9; i++) { p[i] = expf(sc[i] - mval); psum += p[i]; }
  float inv = 1.f / psum;
#pragma unroll
  for (int i = 0; i < 9; i++) p[i] *= inv;
  float Ag[16] = {};
#pragma unroll
  for (int j = 0; j < 3; j++)
#pragma unroll
    for (int i = 0; i < 3; i++) {
      float pv = p[j * 3 + i];
      Ag[j * 4 + i] += w00 * pv;
      Ag[j * 4 + i + 1] += w01 * pv;
      Ag[(j + 1) * 4 + i] += w10 * pv;
      Ag[(j + 1) * 4 + i + 1] += w11 * pv;
    }
  float4 acc = make_float4(0.f, 0.f, 0.f, 0.f);
#pragma unroll
  for (int j = 0; j < 4; j++) {
    int gy = my - 1 + j;
#pragma unroll
    for (int i = 0; i < 4; i++) {
      int gx = mx - 1 + i;
      int idx = gy * Ww + gx;
      float4 vv = *reinterpret_cast<const float4*>(
          kvbuf + (size_t)(base + idx) * kvstride + voff + lane * 4);
      float w = Ag[j * 4 + i];
      acc.x += w * vv.x; acc.y += w * vv.y; acc.z += w * vv.z; acc.w += w * vv.w;
    }
  }
  if (gOff >= 0) {
    float4 gg = *reinterpret_cast<const float4*>(qbuf + row * qstride + gOff + lane * 4);
    acc.x *= gg.x; acc.y *= gg.y; acc.z *= gg.z; acc.w *= gg.w;
  }
  unsigned int p0 = (unsigned int)f2b(acc.x) | ((unsigned int)f2b(acc.y) << 16);
  unsigned int p1 = (unsigned int)f2b(acc.z) | ((unsigned int)f2b(acc.w) << 16);
  *reinterpret_cast<uint2*>(o + row * o_stride + lane * 4) = make_uint2(p0, p1);
  if (mode == 1) {
    float a0 = 0.f, a1 = 0.f;
#pragma unroll
    for (int a = 0; a < 8; a++) {
      if (c == a) { a0 = Ag[2 * a]; a1 = Ag[2 * a + 1]; }
    }
    unsigned int pa = (unsigned int)f2b(a0) | ((unsigned int)f2b(a1) << 16);
    *reinterpret_cast<unsigned int*>(o + row * o_stride + 256 + h * 16 + 2 * c) = pa;
  }
}

// ---------------------------------------------------------------------------
// post self-attn
// ---------------------------------------------------------------------------
__global__ __launch_bounds__(256) void post_self_kernel(
    const float* __restrict__ xcn, const float* __restrict__ n1g,
    const float* __restrict__ n1b, float* __restrict__ out_rpos,
    float* __restrict__ xc2, unsigned short* __restrict__ h1_b) {
  int wv = threadIdx.x >> 6, lane = threadIdx.x & 63;
  int pix = blockIdx.x * 4 + wv;
  const float* row = xcn + (size_t)pix * DSELF;
  float vals[3];
#pragma unroll
  for (int i = 0; i < 3; i++) {
    int c = lane + i * 64;
    vals[i] = (c < DSELF) ? row[c] : 0.f;
  }
#pragma unroll
  for (int i = 0; i < 3; i++) {
    int c = lane + i * 64;
    if (c >= 130 && c < 146) out_rpos[(size_t)pix * 16 + (c - 130)] = vals[i];
  }
#pragma unroll
  for (int i = 0; i < 3; i++) {
    int c = lane + i * 64;
    if (c == 129) vals[i] = 0.f;
  }
  float* x2row = xc2 + (size_t)pix * DCROSS;
#pragma unroll
  for (int i = 0; i < 3; i++) {
    int c = lane + i * 64;
    if (c < DCROSS) x2row[c] = vals[i];
  }
  float s = 0.f;
#pragma unroll
  for (int i = 0; i < 3; i++) { int c = lane + i * 64; if (c < DCROSS) s += vals[i]; }
  float mu = wave_bcast_sum(s) * (1.f / DCROSS);
  float s2 = 0.f;
#pragma unroll
  for (int i = 0; i < 3; i++) {
    int c = lane + i * 64;
    if (c < DCROSS) { float d = vals[i] - mu; s2 += d * d; }
  }
  float var = wave_bcast_sum(s2) * (1.f / DCROSS);
  float rs = rsqrtf(var + 1e-5f);
  unsigned short* h1row = h1_b + (size_t)pix * 160;
#pragma unroll
  for (int i = 0; i < 3; i++) {
    int c = lane + i * 64;
    if (c < 160) {
      float v = (c < DCROSS) ? (vals[i] - mu) * rs * n1g[c] + n1b[c] : 0.f;
      h1row[c] = f2b(v);
    }
  }
}

// ---------------------------------------------------------------------------
// post cross-attn
// ---------------------------------------------------------------------------
__global__ __launch_bounds__(256) void post_cross_kernel(
    const float* __restrict__ xc2n, const float* __restrict__ fs,
    const float* __restrict__ n2g, const float* __restrict__ n2b,
    float* __restrict__ out_f2, float* __restrict__ xob,
    unsigned short* __restrict__ h2_b) {
  int wv = threadIdx.x >> 6, lane = threadIdx.x & 63;
  int pix = blockIdx.x * 4 + wv;
  const float* row = xc2n + (size_t)pix * DCROSS;
  float vals[3];
#pragma unroll
  for (int i = 0; i < 3; i++) {
    int c = lane + i * 64;
    vals[i] = (c < DCROSS) ? row[c] : 0.f;
  }
  if (lane == 0) out_f2[(size_t)pix * 2 + 0] = vals[2] / fs[0];
  if (lane == 1) out_f2[(size_t)pix * 2 + 1] = 0.f;
  float* xrow = xob + (size_t)pix * Cch;
#pragma unroll
  for (int i = 0; i < 2; i++) {
    int c = lane + i * 64;
    xrow[c] = vals[i];
  }
  float s = vals[0] + vals[1];
  float mu = wave_bcast_sum(s) * (1.f / Cch);
  float d0 = vals[0] - mu, d1 = vals[1] - mu;
  float var = wave_bcast_sum(d0 * d0 + d1 * d1) * (1.f / Cch);
  float rs = rsqrtf(var + 1e-5f);
  unsigned short* h2row = h2_b + (size_t)pix * Cch;
#pragma unroll
  for (int i = 0; i < 2; i++) {
    int c = lane + i * 64;
    h2row[c] = f2b((vals[i] - mu) * rs * n2g[c] + n2b[c]);
  }
}

// ---------------------------------------------------------------------------
// depthwise 3x3 SAME on u_b[:, :256] (bf16), + bias, exact gelu, * gate -> bf16
// ---------------------------------------------------------------------------
__global__ __launch_bounds__(256) void dwconv_kernel(
    const unsigned short* __restrict__ ub, const float* __restrict__ dww,
    const float* __restrict__ dwb, unsigned short* __restrict__ aout) {
  int t = blockIdx.x * 256 + threadIdx.x;
  int c8 = (t & 31) * 8;
  int pix = t >> 5;
  int b = pix / Nn, n = pix - b * Nn;
  int py = n / Ww, px = n - py * Ww;
  float acc[8];
#pragma unroll
  for (int j = 0; j < 8; j++) acc[j] = dwb[c8 + j];
#pragma unroll
  for (int ky = 0; ky < 3; ky++) {
    int yy = py + ky - 1;
    if (yy < 0 || yy >= Hh) continue;
#pragma unroll
    for (int kx = 0; kx < 3; kx++) {
      int xx = px + kx - 1;
      if (xx < 0 || xx >= Ww) continue;
      s16x8 uv = *reinterpret_cast<const s16x8*>(
          ub + ((size_t)(b * Nn + yy * Ww + xx)) * 512 + c8);
      const float* wrow = dww + (ky * 3 + kx) * 256 + c8;
#pragma unroll
      for (int j = 0; j < 8; j++)
        acc[j] += b2f((unsigned short)uv[j]) * wrow[j];
    }
  }
  s16x8 gate = *reinterpret_cast<const s16x8*>(ub + (size_t)pix * 512 + 256 + c8);
  s16x8 outp;
#pragma unroll
  for (int j = 0; j < 8; j++) {
    float a = acc[j];
    float ge = 0.5f * a * (1.f + erff(a * 0.70710678118654752f));
    outp[j] = (short)f2b(ge * b2f((unsigned short)gate[j]));
  }
  *reinterpret_cast<s16x8*>(aout + (size_t)pix * 256 + c8) = outp;
}

extern "C" void kernel_launch(void* const* d_in, const int* in_sizes, int n_in,
                              void* d_out, int out_size, void* d_ws, size_t ws_size,
                              hipStream_t stream) {
  (void)in_sizes; (void)n_in; (void)out_size; (void)ws_size;
  const float* x    = (const float*)d_in[0];
  const float* rpos = (const float*)d_in[1];
  const float* field= (const float*)d_in[2];
  const float* fs   = (const float*)d_in[3];
  const float* n0g  = (const float*)d_in[4];
  const float* n0b  = (const float*)d_in[5];
  const float* n1g  = (const float*)d_in[6];
  const float* n1b  = (const float*)d_in[7];
  const float* n2g  = (const float*)d_in[8];
  const float* n2b  = (const float*)d_in[9];
  const float* sq_w = (const float*)d_in[10];
  const float* sk_w = (const float*)d_in[11];
  const float* sv_w = (const float*)d_in[12];
  const float* sp_w = (const float*)d_in[13];
  const float* cq_w = (const float*)d_in[14];
  const float* ck_w = (const float*)d_in[15];
  const float* cv_w = (const float*)d_in[16];
  const float* cg_w = (const float*)d_in[17];
  const float* cp_w = (const float*)d_in[18];
  const float* fc1w = (const float*)d_in[19];
  const float* fc1b = (const float*)d_in[20];
  const float* dww  = (const float*)d_in[21];
  const float* dwb  = (const float*)d_in[22];
  const float* fc2w = (const float*)d_in[23];
  const float* fc2b = (const float*)d_in[24];

  float* ws = (float*)d_ws;
  float* xc    = ws + 0;         // 1345536
  float* xcn   = ws + 1345536;   // 1345536
  float* xc2   = ws + 2691072;   // 1198080
  float* xc2n  = ws + 3889152;   // 1198080
  float* xob   = ws + 5087232;   // 1179648
  unsigned short* xe_b   = (unsigned short*)(ws + 6266880);   // 737280 f
  unsigned short* h1_b   = (unsigned short*)(ws + 7004160);   // 737280 f
  unsigned short* h2_b   = (unsigned short*)(ws + 7741440);   // 589824 f
  float* qkv   = ws + 8331264;   // 7077888 f
  float* qg    = ws + 15409152;  // 4718592 f
  float* kv    = ws + 20127744;  // 4718592 f
  unsigned short* o_b    = (unsigned short*)(ws + 24846336);  // 1179648 f
  unsigned short* ocat_b = (unsigned short*)(ws + 26025984);  // 1769472 f
  unsigned short* warena = (unsigned short*)(ws + 27795456);  // 236160 f
  unsigned short* u_b    = (unsigned short*)qkv;  // qkv dead after self-attn
  unsigned short* aconv_b = o_b;                  // o_b dead after sp GEMM

  float* out_xo   = (float*)d_out;
  float* out_rpos = out_xo + 1179648;
  float* out_f2   = out_xo + 1327104;

  const int oSQKV = 0;
  const int oSP   = 122880;
  const int oCQG  = 160256;
  const int oCKV  = 242176;
  const int oCP   = 324096;
  const int oF1   = 374016;
  const int oF2   = 439552;
  WPack wp;
  auto setw = [&](int i, const float* src, int K, int N, int Kp, int off) {
    wp.d[i].src = src; wp.d[i].K = K; wp.d[i].N = N; wp.d[i].Kp = Kp;
    wp.d[i].dstOff = off;
  };
  setw(0, sq_w, 147, 256, 160, oSQKV);
  setw(1, sk_w, 147, 256, 160, oSQKV + 40960);
  setw(2, sv_w, 147, 256, 160, oSQKV + 81920);
  setw(3, sp_w, 256, 146, 256, oSP);
  setw(4, cq_w, 130, 256, 160, oCQG);
  setw(5, cg_w, 130, 256, 160, oCQG + 40960);
  setw(6, ck_w, 130, 256, 160, oCKV);
  setw(7, cv_w, 130, 256, 160, oCKV + 40960);
  setw(8, cp_w, 384, 130, 384, oCP);
  setw(9, fc1w, 128, 512, 128, oF1);
  setw(10, fc2w, 256, 128, 256, oF2);
  int nblk = 0;
  for (int i = 0; i < 11; i++) {
    wp.d[i].blkOff = nblk;
    nblk += (wp.d[i].N * wp.d[i].Kp + 2047) / 2048;
  }

  dim3 blk(256);
  auto gemm = [&](const unsigned short* A, int Kp, int woff, int N,
                  const float* bias, const float* resid, void* out,
                  int swapA, int act, int obf) {
    if (N <= 384) {
      dim3 grid((N + 63) / 64, Mrows / 32);
      mfma_gemm32_kernel<<<grid, dim3(128), 0, stream>>>(
          A, Kp, warena + woff, N, bias, resid, out, swapA, act, obf);
    } else {
      dim3 grid((N + 63) / 64, Mrows / 64);
      mfma_gemm_kernel<<<grid, blk, 0, stream>>>(
          A, Kp, warena + woff, N, bias, resid, out, swapA, act, obf);
    }
  };

  // prep + fused weight conversion
  prep_kernel<<<nblk + 2304, blk, 0, stream>>>(wp, warena, nblk, x, rpos, field,
                                               fs, n0g, n0b, xc, xe_b);
  gemm(xe_b, 160, oSQKV, 768, nullptr, nullptr, qkv, 0, 0, 0);
  attn_wave_kernel<<<2304, blk, 0, stream>>>(qkv, 768, -1, qkv, 768, 256, 512,
                                             rpos, nullptr, fs, o_b, 256, 0);
  gemm(o_b, 256, oSP, 146, nullptr, xc, xcn, 0, 0, 0);
  post_self_kernel<<<2304, blk, 0, stream>>>(xcn, n1g, n1b, out_rpos, xc2, h1_b);
  gemm(h1_b, 160, oCQG, 512, nullptr, nullptr, qg, 0, 2, 0);
  gemm(h1_b, 160, oCKV, 512, nullptr, nullptr, kv, 1, 0, 0);
  attn_wave_kernel<<<2304, blk, 0, stream>>>(qg, 512, 256, kv, 512, 0, 256,
                                             nullptr, xc2, fs, ocat_b, 384, 1);
  gemm(ocat_b, 384, oCP, 130, nullptr, xc2, xc2n, 0, 0, 0);
  post_cross_kernel<<<2304, blk, 0, stream>>>(xc2n, fs, n2g, n2b, out_f2, xob, h2_b);
  gemm(h2_b, 128, oF1, 512, fc1b, nullptr, u_b, 0, 0, 1);
  dwconv_kernel<<<1152, blk, 0, stream>>>(u_b, dww, dwb, aconv_b);
  gemm(aconv_b, 256, oF2, 128, fc2b, xob, out_xo, 0, 0, 0);
}

// Round 8
// 147.718 us; speedup vs baseline: 3.9090x; 1.0891x over previous
//
#include <hip/hip_runtime.h>
#include <math.h>

namespace {
constexpr int Bn = 2, Hh = 48, Ww = 96, Cch = 128;
constexpr int Nn = Hh * Ww;            // 4608
constexpr int NHh = 8;
constexpr int DSELF = 146, ESELF = 147, DCROSS = 130;
constexpr int Mrows = Bn * Nn;         // 9216
constexpr float SCALEf = 0.17677669529663687f; // 32^-0.5
}

typedef float f32x4 __attribute__((ext_vector_type(4)));
typedef short s16x8 __attribute__((ext_vector_type(8)));
typedef _Float16 h16x4 __attribute__((ext_vector_type(4)));

__device__ __forceinline__ unsigned short f2b(float f) {
  unsigned int u = __float_as_uint(f);
  u = u + 0x7fffu + ((u >> 16) & 1u);
  return (unsigned short)(u >> 16);
}
__device__ __forceinline__ float b2f(unsigned short u) {
  return __uint_as_float((unsigned int)u << 16);
}
__device__ __forceinline__ float4 ld4h(const _Float16* p) {
  h16x4 h = *reinterpret_cast<const h16x4*>(p);
  return make_float4((float)h[0], (float)h[1], (float)h[2], (float)h[3]);
}

__device__ __forceinline__ f32x4 mfma_bf16(s16x8 a, s16x8 b, f32x4 c) {
  f32x4 d;
  asm volatile("v_mfma_f32_16x16x32_bf16 %0, %1, %2, %3"
               : "=&v"(d) : "v"(a), "v"(b), "v"(c));
  return d;
}

__device__ __forceinline__ float wave_bcast_sum(float v) {
#pragma unroll
  for (int off = 32; off > 0; off >>= 1) v += __shfl_down(v, off);
  return __shfl(v, 0);
}

// ---------------------------------------------------------------------------
// weight descs for fused convert (runs inside prep launch)
// ---------------------------------------------------------------------------
struct WDesc { const float* src; int K, N, Kp, dstOff, blkOff; };
struct WPack { WDesc d[11]; };

__device__ __forceinline__ void convert_w_body(const WPack& p, unsigned short* dst,
                                               int bi) {
  int mi = 0;
#pragma unroll
  for (int i = 1; i < 11; i++) if (bi >= p.d[i].blkOff) mi = i;
  WDesc w = p.d[mi];
  int e = (bi - w.blkOff) * 2048 + threadIdx.x * 8;
  int total = w.N * w.Kp;
  if (e >= total) return;
  int n = e / w.Kp, k0 = e - n * w.Kp;
  s16x8 pack;
#pragma unroll
  for (int j = 0; j < 8; j++) {
    int kk = k0 + j;
    float vv = (kk < w.K) ? w.src[(size_t)kk * w.N + n] : 0.f;
    pack[j] = (short)f2b(vv);
  }
  *reinterpret_cast<s16x8*>(dst + w.dstOff + e) = pack;
}

// ---------------------------------------------------------------------------
// GEMM epilogue helper: split destinations.
//   col <  colSplit -> out0 (f32 or bf16 per mode0), row stride colSplit,
//                      resid (stride colSplit) added here
//   col >= colSplit -> out1 fp16, row stride (N - colSplit)
// act: 0 none, 1 silu all, 3 silu on cols in [256,512)
// swapMode: 0 none, 1 all rows swapped, 2 swap iff n0 >= colSplit
// ---------------------------------------------------------------------------
__device__ __forceinline__ void gemm_store(
    float vv, int row, int col, int N, int colSplit,
    const float* __restrict__ bias, const float* __restrict__ resid,
    void* __restrict__ out0, void* __restrict__ out1, int mode0, int act) {
  if (bias) vv += bias[col];
  if (act == 1 || (act == 3 && col >= 256 && col < 512))
    vv = vv / (1.f + expf(-vv));
  if (col < colSplit) {
    if (resid) vv += resid[(size_t)row * colSplit + col];
    if (mode0)
      ((unsigned short*)out0)[(size_t)row * colSplit + col] = f2b(vv);
    else
      ((float*)out0)[(size_t)row * colSplit + col] = vv;
  } else {
    ((_Float16*)out1)[(size_t)row * (N - colSplit) + (col - colSplit)] =
        (_Float16)vv;
  }
}

// ---------------------------------------------------------------------------
// bf16 MFMA GEMM, 64x64 tile, 256 thr (4 waves x 32x32), BK=32
// ---------------------------------------------------------------------------
__global__ __launch_bounds__(256) void mfma_gemm_kernel(
    const unsigned short* __restrict__ A, int Kp,
    const unsigned short* __restrict__ Wt, int N,
    const float* __restrict__ bias, const float* __restrict__ resid,
    void* __restrict__ out0, void* __restrict__ out1, int colSplit,
    int mode0, int swapMode, int act) {
  __shared__ unsigned short As[64 * 40];
  __shared__ unsigned short Bs[64 * 40];
  int tid = threadIdx.x;
  int m0 = blockIdx.y * 64, n0 = blockIdx.x * 64;
  int lane = tid & 63, wv = tid >> 6;
  int wr = wv >> 1, wc = wv & 1;
  int lr = lane & 15, lk = (lane >> 4) * 8;
  int sr = tid >> 2, sk8 = (tid & 3) * 8;
  int am = m0 + sr;
  int swp = (swapMode == 1) || (swapMode == 2 && n0 >= colSplit);
  if (swp) am = (am < Mrows / 2) ? am + Mrows / 2 : am - Mrows / 2;
  const unsigned short* aptr = A + (size_t)am * Kp + sk8;
  int bn = n0 + sr;
  const unsigned short* bptr = (bn < N) ? Wt + (size_t)bn * Kp + sk8 : nullptr;
  f32x4 acc00 = {}, acc01 = {}, acc10 = {}, acc11 = {};
  for (int k0 = 0; k0 < Kp; k0 += 32) {
    s16x8 av = *reinterpret_cast<const s16x8*>(aptr + k0);
    s16x8 bv = {};
    if (bptr) bv = *reinterpret_cast<const s16x8*>(bptr + k0);
    *reinterpret_cast<s16x8*>(&As[sr * 40 + sk8]) = av;
    *reinterpret_cast<s16x8*>(&Bs[sr * 40 + sk8]) = bv;
    __syncthreads();
    s16x8 a0 = *reinterpret_cast<const s16x8*>(&As[(wr * 32 + lr) * 40 + lk]);
    s16x8 a1 = *reinterpret_cast<const s16x8*>(&As[(wr * 32 + 16 + lr) * 40 + lk]);
    s16x8 b0 = *reinterpret_cast<const s16x8*>(&Bs[(wc * 32 + lr) * 40 + lk]);
    s16x8 b1 = *reinterpret_cast<const s16x8*>(&Bs[(wc * 32 + 16 + lr) * 40 + lk]);
    acc00 = mfma_bf16(a0, b0, acc00);
    acc01 = mfma_bf16(a0, b1, acc01);
    acc10 = mfma_bf16(a1, b0, acc10);
    acc11 = mfma_bf16(a1, b1, acc11);
    __syncthreads();
  }
  int rowBase = m0 + wr * 32 + (lane >> 4) * 4;
  f32x4 accs[2][2] = {{acc00, acc01}, {acc10, acc11}};
#pragma unroll
  for (int fc = 0; fc < 2; fc++) {
    int col = n0 + wc * 32 + fc * 16 + lr;
    if (col >= N) continue;
#pragma unroll
    for (int fr = 0; fr < 2; fr++) {
#pragma unroll
      for (int r = 0; r < 4; r++) {
        int row = rowBase + fr * 16 + r;
        gemm_store(accs[fr][fc][r], row, col, N, colSplit, bias, resid,
                   out0, out1, mode0, act);
      }
    }
  }
}

// ---------------------------------------------------------------------------
// bf16 MFMA GEMM, 32x64 tile, 128 thr (2 waves x 32x32) — small N
// ---------------------------------------------------------------------------
__global__ __launch_bounds__(128) void mfma_gemm32_kernel(
    const unsigned short* __restrict__ A, int Kp,
    const unsigned short* __restrict__ Wt, int N,
    const float* __restrict__ bias, const float* __restrict__ resid,
    void* __restrict__ out0, void* __restrict__ out1, int colSplit,
    int mode0, int swapMode, int act) {
  __shared__ unsigned short As[32 * 40];
  __shared__ unsigned short Bs[64 * 40];
  int tid = threadIdx.x;
  int m0 = blockIdx.y * 32, n0 = blockIdx.x * 64;
  int lane = tid & 63, wv = tid >> 6;
  int lr = lane & 15, lk = (lane >> 4) * 8;
  int sr = tid >> 2, sk8 = (tid & 3) * 8;
  int am = m0 + sr;
  int swp = (swapMode == 1) || (swapMode == 2 && n0 >= colSplit);
  if (swp) am = (am < Mrows / 2) ? am + Mrows / 2 : am - Mrows / 2;
  const unsigned short* aptr = A + (size_t)am * Kp + sk8;
  int bn0 = n0 + sr, bn1 = n0 + sr + 32;
  const unsigned short* bptr0 = (bn0 < N) ? Wt + (size_t)bn0 * Kp + sk8 : nullptr;
  const unsigned short* bptr1 = (bn1 < N) ? Wt + (size_t)bn1 * Kp + sk8 : nullptr;
  f32x4 acc00 = {}, acc01 = {}, acc10 = {}, acc11 = {};
  for (int k0 = 0; k0 < Kp; k0 += 32) {
    s16x8 av = *reinterpret_cast<const s16x8*>(aptr + k0);
    s16x8 bv0 = {}, bv1 = {};
    if (bptr0) bv0 = *reinterpret_cast<const s16x8*>(bptr0 + k0);
    if (bptr1) bv1 = *reinterpret_cast<const s16x8*>(bptr1 + k0);
    *reinterpret_cast<s16x8*>(&As[sr * 40 + sk8]) = av;
    *reinterpret_cast<s16x8*>(&Bs[sr * 40 + sk8]) = bv0;
    *reinterpret_cast<s16x8*>(&Bs[(sr + 32) * 40 + sk8]) = bv1;
    __syncthreads();
    s16x8 a0 = *reinterpret_cast<const s16x8*>(&As[lr * 40 + lk]);
    s16x8 a1 = *reinterpret_cast<const s16x8*>(&As[(16 + lr) * 40 + lk]);
    s16x8 b0 = *reinterpret_cast<const s16x8*>(&Bs[(wv * 32 + lr) * 40 + lk]);
    s16x8 b1 = *reinterpret_cast<const s16x8*>(&Bs[(wv * 32 + 16 + lr) * 40 + lk]);
    acc00 = mfma_bf16(a0, b0, acc00);
    acc01 = mfma_bf16(a0, b1, acc01);
    acc10 = mfma_bf16(a1, b0, acc10);
    acc11 = mfma_bf16(a1, b1, acc11);
    __syncthreads();
  }
  int rowBase = m0 + (lane >> 4) * 4;
  f32x4 accs[2][2] = {{acc00, acc01}, {acc10, acc11}};
#pragma unroll
  for (int fc = 0; fc < 2; fc++) {
    int col = n0 + wv * 32 + fc * 16 + lr;
    if (col >= N) continue;
#pragma unroll
    for (int fr = 0; fr < 2; fr++) {
#pragma unroll
      for (int r = 0; r < 4; r++) {
        int row = rowBase + fr * 16 + r;
        gemm_store(accs[fr][fc][r], row, col, N, colSplit, bias, resid,
                   out0, out1, mode0, act);
      }
    }
  }
}

// ---------------------------------------------------------------------------
// prep (+ fused weight convert in first nconv blocks)
// ---------------------------------------------------------------------------
__global__ __launch_bounds__(256) void prep_kernel(
    WPack wp, unsigned short* __restrict__ warena, int nconv,
    const float* __restrict__ x, const float* __restrict__ rpos,
    const float* __restrict__ field, const float* __restrict__ fs,
    const float* __restrict__ n0g, const float* __restrict__ n0b,
    float* __restrict__ xc, unsigned short* __restrict__ xe_b) {
  if (blockIdx.x < (unsigned)nconv) {
    convert_w_body(wp, warena, blockIdx.x);
    return;
  }
  int wv = threadIdx.x >> 6, lane = threadIdx.x & 63;
  int pix = (blockIdx.x - nconv) * 4 + wv;
  int b = pix / Nn, n = pix - b * Nn;
  int py = n / Ww, px = n - py * Ww;
  const float* xrow = x + (size_t)pix * Cch;
  const float* rrow = rpos + (size_t)pix * 16;
  float f0 = field[(size_t)pix * 2 + 0], f1 = field[(size_t)pix * 2 + 1];
  float fsx = fs[0], fsy = fs[1];
  float vals[3];
#pragma unroll
  for (int i = 0; i < 3; i++) {
    int c = lane + i * 64;
    float v = 0.f;
    if (c < Cch) v = xrow[c];
    else if (c == 128) v = f0 * fsx;
    else if (c == 129) v = f1 * fsy;
    else if (c < DSELF) v = rrow[c - 130];
    vals[i] = v;
  }
  float* xcrow = xc + (size_t)pix * DSELF;
#pragma unroll
  for (int i = 0; i < 3; i++) {
    int c = lane + i * 64;
    if (c < DSELF) xcrow[c] = vals[i];
  }
  float s = 0.f;
#pragma unroll
  for (int i = 0; i < 3; i++) { int c = lane + i * 64; if (c < DSELF) s += vals[i]; }
  float mu = wave_bcast_sum(s) * (1.f / DSELF);
  float s2 = 0.f;
#pragma unroll
  for (int i = 0; i < 3; i++) {
    int c = lane + i * 64;
    if (c < DSELF) { float d = vals[i] - mu; s2 += d * d; }
  }
  float var = wave_bcast_sum(s2) * (1.f / DSELF);
  float rs = rsqrtf(var + 1e-5f);
  float noc = 0.f;
  if (lane == 0) {
    float ox = fminf(fmaxf(f0 + (float)px, 0.f), (float)(Ww - 1));
    float oy = fminf(fmaxf(f1 + (float)py, 0.f), (float)(Hh - 1));
    float x0f = fminf(fmaxf(floorf(ox), 0.f), (float)(Ww - 2));
    float y0f = fminf(fmaxf(floorf(oy), 0.f), (float)(Hh - 2));
    int x0 = (int)x0f, y0 = (int)y0f;
    float wx = ox - x0f, wy = oy - y0f;
    const float* fo = field + (size_t)(1 - b) * Nn * 2;
    const float* p00 = fo + ((size_t)y0 * Ww + x0) * 2;
    const float* p10 = fo + ((size_t)(y0 + 1) * Ww + x0) * 2;
    float v0 = (1.f - wy) * ((1.f - wx) * p00[0] + wx * p00[2]) +
               wy * ((1.f - wx) * p10[0] + wx * p10[2]);
    float v1 = (1.f - wy) * ((1.f - wx) * p00[1] + wx * p00[3]) +
               wy * ((1.f - wx) * p10[1] + wx * p10[3]);
    float diff = fabsf(f0 + v0) + fabsf(f1 + v1);
    noc = (diff < 2.f) ? 1.f : 0.f;
  }
  noc = __shfl(noc, 0);
  unsigned short* xerow = xe_b + (size_t)pix * 160;
#pragma unroll
  for (int i = 0; i < 3; i++) {
    int c = lane + i * 64;
    if (c < 160) {
      float v;
      if (c < DSELF) v = (vals[i] - mu) * rs * n0g[c] + n0b[c];
      else if (c == 146) v = noc;
      else v = 0.f;
      xerow[c] = f2b(v);
    }
  }
}

// ---------------------------------------------------------------------------
// windowed match attention, one WAVE per pixel.
// q (f32, stride qstride; optional gate at +gOff); k/v fp16 in kvbuf
// (stride 512, k at +0, v at +256). bf16 outputs.
// ---------------------------------------------------------------------------
__global__ __launch_bounds__(256) void attn_wave_kernel(
    const float* __restrict__ qbuf, int qstride, int gOff,
    const _Float16* __restrict__ kvbuf,
    const float* __restrict__ rpos, const float* __restrict__ xc2,
    const float* __restrict__ fs, unsigned short* __restrict__ o, int o_stride,
    int mode) {
  int wv = threadIdx.x >> 6, lane = threadIdx.x & 63;
  int pix = blockIdx.x * 4 + wv;
  int b = pix / Nn, n = pix - b * Nn;
  int py = n / Ww, px = n - py * Ww;
  int h = lane >> 3, c = lane & 7;
  size_t row = (size_t)pix;
  float ox, oy;
  if (mode == 0) {
    ox = rpos[row * 16 + 2 * h] + (float)px;
    oy = rpos[row * 16 + 2 * h + 1] + (float)py;
  } else {
    ox = xc2[row * DCROSS + 128] / fs[0] + (float)px;
    oy = (float)py;
  }
  ox = fminf(fmaxf(ox, 1.0f), 93.999f);
  oy = fminf(fmaxf(oy, 1.0f), 45.999f);
  float mxf = floorf(ox), myf = floorf(oy);
  float fx = ox - mxf, fy = oy - myf;
  int mx = (int)mxf, my = (int)myf;
  int base = b * Nn;

  float4 qv = *reinterpret_cast<const float4*>(qbuf + row * qstride + lane * 4);
  float s[16];
#pragma unroll
  for (int j = 0; j < 4; j++) {
    int gy = my - 1 + j;
#pragma unroll
    for (int i = 0; i < 4; i++) {
      int gx = mx - 1 + i;
      int idx = gy * Ww + gx;
      float4 kv = ld4h(kvbuf + (size_t)(base + idx) * 512 + lane * 4);
      float d = qv.x * kv.x + qv.y * kv.y + qv.z * kv.z + qv.w * kv.w;
      d += __shfl_xor(d, 1);
      d += __shfl_xor(d, 2);
      d += __shfl_xor(d, 4);
      s[j * 4 + i] = d * SCALEf;
    }
  }
  float w00 = (1.f - fy) * (1.f - fx), w01 = (1.f - fy) * fx;
  float w10 = fy * (1.f - fx), w11 = fy * fx;
  float sc[9];
#pragma unroll
  for (int j = 0; j < 3; j++)
#pragma unroll
    for (int i = 0; i < 3; i++)
      sc[j * 3 + i] = w00 * s[j * 4 + i] + w01 * s[j * 4 + i + 1] +
                      w10 * s[(j + 1) * 4 + i] + w11 * s[(j + 1) * 4 + i + 1];
  float mval = sc[0];
#pragma unroll
  for (int i = 1; i < 9; i++) mval = fmaxf(mval, sc[i]);
  float p[9], psum = 0.f;
#pragma unroll
  for (int i = 0; i < 9; i++) { p[i] = expf(sc[i] - mval); psum += p[i]; }
  float inv = 1.f / psum;
#pragma unroll
  for (int i = 0; i < 9; i++) p[i] *= inv;
  float Ag[16] = {};
#pragma unroll
  for (int j = 0; j < 3; j++)
#pragma unroll
    for (int i = 0; i < 3; i++) {
      float pv = p[j * 3 + i];
      Ag[j * 4 + i] += w00 * pv;
      Ag[j * 4 + i + 1] += w01 * pv;
      Ag[(j + 1) * 4 + i] += w10 * pv;
      Ag[(j + 1) * 4 + i + 1] += w11 * pv;
    }
  float4 acc = make_float4(0.f, 0.f, 0.f, 0.f);
#pragma unroll
  for (int j = 0; j < 4; j++) {
    int gy = my - 1 + j;
#pragma unroll
    for (int i = 0; i < 4; i++) {
      int gx = mx - 1 + i;
      int idx = gy * Ww + gx;
      float4 vv = ld4h(kvbuf + (size_t)(base + idx) * 512 + 256 + lane * 4);
      float w = Ag[j * 4 + i];
      acc.x += w * vv.x; acc.y += w * vv.y; acc.z += w * vv.z; acc.w += w * vv.w;
    }
  }
  if (gOff >= 0) {
    float4 gg = *reinterpret_cast<const float4*>(qbuf + row * qstride + gOff + lane * 4);
    acc.x *= gg.x; acc.y *= gg.y; acc.z *= gg.z; acc.w *= gg.w;
  }
  unsigned int p0 = (unsigned int)f2b(acc.x) | ((unsigned int)f2b(acc.y) << 16);
  unsigned int p1 = (unsigned int)f2b(acc.z) | ((unsigned int)f2b(acc.w) << 16);
  *reinterpret_cast<uint2*>(o + row * o_stride + lane * 4) = make_uint2(p0, p1);
  if (mode == 1) {
    float a0 = 0.f, a1 = 0.f;
#pragma unroll
    for (int a = 0; a < 8; a++) {
      if (c == a) { a0 = Ag[2 * a]; a1 = Ag[2 * a + 1]; }
    }
    unsigned int pa = (unsigned int)f2b(a0) | ((unsigned int)f2b(a1) << 16);
    *reinterpret_cast<unsigned int*>(o + row * o_stride + 256 + h * 16 + 2 * c) = pa;
  }
}

// ---------------------------------------------------------------------------
// post self-attn
// ---------------------------------------------------------------------------
__global__ __launch_bounds__(256) void post_self_kernel(
    const float* __restrict__ xcn, const float* __restrict__ n1g,
    const float* __restrict__ n1b, float* __restrict__ out_rpos,
    float* __restrict__ xc2, unsigned short* __restrict__ h1_b) {
  int wv = threadIdx.x >> 6, lane = threadIdx.x & 63;
  int pix = blockIdx.x * 4 + wv;
  const float* row = xcn + (size_t)pix * DSELF;
  float vals[3];
#pragma unroll
  for (int i = 0; i < 3; i++) {
    int c = lane + i * 64;
    vals[i] = (c < DSELF) ? row[c] : 0.f;
  }
#pragma unroll
  for (int i = 0; i < 3; i++) {
    int c = lane + i * 64;
    if (c >= 130 && c < 146) out_rpos[(size_t)pix * 16 + (c - 130)] = vals[i];
  }
#pragma unroll
  for (int i = 0; i < 3; i++) {
    int c = lane + i * 64;
    if (c == 129) vals[i] = 0.f;
  }
  float* x2row = xc2 + (size_t)pix * DCROSS;
#pragma unroll
  for (int i = 0; i < 3; i++) {
    int c = lane + i * 64;
    if (c < DCROSS) x2row[c] = vals[i];
  }
  float s = 0.f;
#pragma unroll
  for (int i = 0; i < 3; i++) { int c = lane + i * 64; if (c < DCROSS) s += vals[i]; }
  float mu = wave_bcast_sum(s) * (1.f / DCROSS);
  float s2 = 0.f;
#pragma unroll
  for (int i = 0; i < 3; i++) {
    int c = lane + i * 64;
    if (c < DCROSS) { float d = vals[i] - mu; s2 += d * d; }
  }
  float var = wave_bcast_sum(s2) * (1.f / DCROSS);
  float rs = rsqrtf(var + 1e-5f);
  unsigned short* h1row = h1_b + (size_t)pix * 160;
#pragma unroll
  for (int i = 0; i < 3; i++) {
    int c = lane + i * 64;
    if (c < 160) {
      float v = (c < DCROSS) ? (vals[i] - mu) * rs * n1g[c] + n1b[c] : 0.f;
      h1row[c] = f2b(v);
    }
  }
}

// ---------------------------------------------------------------------------
// post cross-attn
// ---------------------------------------------------------------------------
__global__ __launch_bounds__(256) void post_cross_kernel(
    const float* __restrict__ xc2n, const float* __restrict__ fs,
    const float* __restrict__ n2g, const float* __restrict__ n2b,
    float* __restrict__ out_f2, float* __restrict__ xob,
    unsigned short* __restrict__ h2_b) {
  int wv = threadIdx.x >> 6, lane = threadIdx.x & 63;
  int pix = blockIdx.x * 4 + wv;
  const float* row = xc2n + (size_t)pix * DCROSS;
  float vals[3];
#pragma unroll
  for (int i = 0; i < 3; i++) {
    int c = lane + i * 64;
    vals[i] = (c < DCROSS) ? row[c] : 0.f;
  }
  if (lane == 0) out_f2[(size_t)pix * 2 + 0] = vals[2] / fs[0];
  if (lane == 1) out_f2[(size_t)pix * 2 + 1] = 0.f;
  float* xrow = xob + (size_t)pix * Cch;
#pragma unroll
  for (int i = 0; i < 2; i++) {
    int c = lane + i * 64;
    xrow[c] = vals[i];
  }
  float s = vals[0] + vals[1];
  float mu = wave_bcast_sum(s) * (1.f / Cch);
  float d0 = vals[0] - mu, d1 = vals[1] - mu;
  float var = wave_bcast_sum(d0 * d0 + d1 * d1) * (1.f / Cch);
  float rs = rsqrtf(var + 1e-5f);
  unsigned short* h2row = h2_b + (size_t)pix * Cch;
#pragma unroll
  for (int i = 0; i < 2; i++) {
    int c = lane + i * 64;
    h2row[c] = f2b((vals[i] - mu) * rs * n2g[c] + n2b[c]);
  }
}

// ---------------------------------------------------------------------------
// depthwise 3x3 SAME on u_b[:, :256] (bf16), + bias, exact gelu, * gate -> bf16
// ---------------------------------------------------------------------------
__global__ __launch_bounds__(256) void dwconv_kernel(
    const unsigned short* __restrict__ ub, const float* __restrict__ dww,
    const float* __restrict__ dwb, unsigned short* __restrict__ aout) {
  int t = blockIdx.x * 256 + threadIdx.x;
  int c8 = (t & 31) * 8;
  int pix = t >> 5;
  int b = pix / Nn, n = pix - b * Nn;
  int py = n / Ww, px = n - py * Ww;
  float acc[8];
#pragma unroll
  for (int j = 0; j < 8; j++) acc[j] = dwb[c8 + j];
#pragma unroll
  for (int ky = 0; ky < 3; ky++) {
    int yy = py + ky - 1;
    if (yy < 0 || yy >= Hh) continue;
#pragma unroll
    for (int kx = 0; kx < 3; kx++) {
      int xx = px + kx - 1;
      if (xx < 0 || xx >= Ww) continue;
      s16x8 uv = *reinterpret_cast<const s16x8*>(
          ub + ((size_t)(b * Nn + yy * Ww + xx)) * 512 + c8);
      const float* wrow = dww + (ky * 3 + kx) * 256 + c8;
#pragma unroll
      for (int j = 0; j < 8; j++)
        acc[j] += b2f((unsigned short)uv[j]) * wrow[j];
    }
  }
  s16x8 gate = *reinterpret_cast<const s16x8*>(ub + (size_t)pix * 512 + 256 + c8);
  s16x8 outp;
#pragma unroll
  for (int j = 0; j < 8; j++) {
    float a = acc[j];
    float ge = 0.5f * a * (1.f + erff(a * 0.70710678118654752f));
    outp[j] = (short)f2b(ge * b2f((unsigned short)gate[j]));
  }
  *reinterpret_cast<s16x8*>(aout + (size_t)pix * 256 + c8) = outp;
}

extern "C" void kernel_launch(void* const* d_in, const int* in_sizes, int n_in,
                              void* d_out, int out_size, void* d_ws, size_t ws_size,
                              hipStream_t stream) {
  (void)in_sizes; (void)n_in; (void)out_size; (void)ws_size;
  const float* x    = (const float*)d_in[0];
  const float* rpos = (const float*)d_in[1];
  const float* field= (const float*)d_in[2];
  const float* fs   = (const float*)d_in[3];
  const float* n0g  = (const float*)d_in[4];
  const float* n0b  = (const float*)d_in[5];
  const float* n1g  = (const float*)d_in[6];
  const float* n1b  = (const float*)d_in[7];
  const float* n2g  = (const float*)d_in[8];
  const float* n2b  = (const float*)d_in[9];
  const float* sq_w = (const float*)d_in[10];
  const float* sk_w = (const float*)d_in[11];
  const float* sv_w = (const float*)d_in[12];
  const float* sp_w = (const float*)d_in[13];
  const float* cq_w = (const float*)d_in[14];
  const float* ck_w = (const float*)d_in[15];
  const float* cv_w = (const float*)d_in[16];
  const float* cg_w = (const float*)d_in[17];
  const float* cp_w = (const float*)d_in[18];
  const float* fc1w = (const float*)d_in[19];
  const float* fc1b = (const float*)d_in[20];
  const float* dww  = (const float*)d_in[21];
  const float* dwb  = (const float*)d_in[22];
  const float* fc2w = (const float*)d_in[23];
  const float* fc2b = (const float*)d_in[24];

  float* ws = (float*)d_ws;
  float* xc    = ws + 0;         // 1345536
  float* xcn   = ws + 1345536;   // 1345536 -> 2691072
  float* xc2   = ws + 2691072;   // 1198080 -> 3889152
  float* xc2n  = ws + 3889152;   // 1198080 -> 5087232
  float* xob   = ws + 5087232;   // 1179648 -> 6266880
  unsigned short* xe_b = (unsigned short*)(ws + 6266880);  // 737280 -> 7004160
  unsigned short* h1_b = (unsigned short*)(ws + 7004160);  // 737280 -> 7741440
  unsigned short* h2_b = (unsigned short*)(ws + 7741440);  // 589824 -> 8331264
  float* q32   = ws + 8331264;   // 9216*256 f32 = 2359296 -> 10690560
  _Float16* kv16 = (_Float16*)(ws + 10690560);  // 9216*512 h = 2359296 -> 13049856
  float* qg    = ws + 13049856;  // 9216*512 f32 = 4718592 -> 17768448
  unsigned short* o_b    = (unsigned short*)(ws + 17768448);  // 1179648 -> 18948096
  unsigned short* ocat_b = (unsigned short*)(ws + 18948096);  // 1769472 -> 20717568
  unsigned short* warena = (unsigned short*)(ws + 20717568);  // 236160 -> 20953728
  unsigned short* u_b    = (unsigned short*)qg;  // qg dead after cross attn
  unsigned short* aconv_b = o_b;                 // o_b dead after sp GEMM

  float* out_xo   = (float*)d_out;
  float* out_rpos = out_xo + 1179648;
  float* out_f2   = out_xo + 1327104;

  // arena (ushort offsets): sq|sk|sv then cq|cg|ck|cv contiguous
  const int oSQKV = 0;          // 768*160
  const int oSP   = 122880;     // 146*256
  const int oCQGKV= 160256;     // 1024*160
  const int oCP   = 324096;     // 130*384
  const int oF1   = 374016;     // 512*128
  const int oF2   = 439552;     // 128*256 (ends 472320)
  WPack wp;
  auto setw = [&](int i, const float* src, int K, int N, int Kp, int off) {
    wp.d[i].src = src; wp.d[i].K = K; wp.d[i].N = N; wp.d[i].Kp = Kp;
    wp.d[i].dstOff = off;
  };
  setw(0, sq_w, 147, 256, 160, oSQKV);
  setw(1, sk_w, 147, 256, 160, oSQKV + 40960);
  setw(2, sv_w, 147, 256, 160, oSQKV + 81920);
  setw(3, sp_w, 256, 146, 256, oSP);
  setw(4, cq_w, 130, 256, 160, oCQGKV);
  setw(5, cg_w, 130, 256, 160, oCQGKV + 40960);
  setw(6, ck_w, 130, 256, 160, oCQGKV + 81920);
  setw(7, cv_w, 130, 256, 160, oCQGKV + 122880);
  setw(8, cp_w, 384, 130, 384, oCP);
  setw(9, fc1w, 128, 512, 128, oF1);
  setw(10, fc2w, 256, 128, 256, oF2);
  int nblk = 0;
  for (int i = 0; i < 11; i++) {
    wp.d[i].blkOff = nblk;
    nblk += (wp.d[i].N * wp.d[i].Kp + 2047) / 2048;
  }

  dim3 blk(256);
  auto gemm = [&](const unsigned short* A, int Kp, int woff, int N,
                  const float* bias, const float* resid, void* out0, void* out1,
                  int colSplit, int mode0, int swapMode, int act) {
    if (N <= 384) {
      dim3 grid((N + 63) / 64, Mrows / 32);
      mfma_gemm32_kernel<<<grid, dim3(128), 0, stream>>>(
          A, Kp, warena + woff, N, bias, resid, out0, out1, colSplit, mode0,
          swapMode, act);
    } else {
      dim3 grid((N + 63) / 64, Mrows / 64);
      mfma_gemm_kernel<<<grid, blk, 0, stream>>>(
          A, Kp, warena + woff, N, bias, resid, out0, out1, colSplit, mode0,
          swapMode, act);
    }
  };

  // 1. prep + fused weight conversion
  prep_kernel<<<nblk + 2304, blk, 0, stream>>>(wp, warena, nblk, x, rpos, field,
                                               fs, n0g, n0b, xc, xe_b);
  // 2. self QKV: q -> q32 (f32), k|v -> kv16 (fp16)
  gemm(xe_b, 160, oSQKV, 768, nullptr, nullptr, q32, kv16, 256, 0, 0, 0);
  // 3. self attention
  attn_wave_kernel<<<2304, blk, 0, stream>>>(q32, 256, -1, kv16, rpos, nullptr,
                                             fs, o_b, 256, 0);
  // 4. sp projection + residual
  gemm(o_b, 256, oSP, 146, nullptr, xc, xcn, nullptr, 146, 0, 0, 0);
  // 5. post-self
  post_self_kernel<<<2304, blk, 0, stream>>>(xcn, n1g, n1b, out_rpos, xc2, h1_b);
  // 6. cross q|g|k|v fused: q,g -> qg (f32, silu on [256,512)), k|v -> kv16
  //    (swapped A for n0>=512)
  gemm(h1_b, 160, oCQGKV, 1024, nullptr, nullptr, qg, kv16, 512, 0, 2, 3);
  // 7. cross attention (gated, writes Af)
  attn_wave_kernel<<<2304, blk, 0, stream>>>(qg, 512, 256, kv16, nullptr, xc2,
                                             fs, ocat_b, 384, 1);
  // 8. cp projection + residual
  gemm(ocat_b, 384, oCP, 130, nullptr, xc2, xc2n, nullptr, 130, 0, 0, 0);
  // 9. post-cross
  post_cross_kernel<<<2304, blk, 0, stream>>>(xc2n, fs, n2g, n2b, out_f2, xob, h2_b);
  // 10. fc1 -> u bf16
  gemm(h2_b, 128, oF1, 512, fc1b, nullptr, u_b, nullptr, 512, 1, 0, 0);
  // 11. depthwise conv + gelu + gate
  dwconv_kernel<<<1152, blk, 0, stream>>>(u_b, dww, dwb, aconv_b);
  // 12. fc2 + residual
  gemm(aconv_b, 256, oF2, 128, fc2b, xob, out_xo, nullptr, 128, 0, 0, 0);
}

// Round 12
// 147.626 us; speedup vs baseline: 3.9114x; 1.0006x over previous
//
#include <hip/hip_runtime.h>
#include <math.h>

namespace {
constexpr int Bn = 2, Hh = 48, Ww = 96, Cch = 128;
constexpr int Nn = Hh * Ww;            // 4608
constexpr int NHh = 8;
constexpr int DSELF = 146, ESELF = 147, DCROSS = 130;
constexpr int Mrows = Bn * Nn;         // 9216
constexpr float SCALEf = 0.17677669529663687f; // 32^-0.5
}

typedef float f32x4 __attribute__((ext_vector_type(4)));
typedef short s16x8 __attribute__((ext_vector_type(8)));
typedef _Float16 h16x4 __attribute__((ext_vector_type(4)));

__device__ __forceinline__ unsigned short f2b(float f) {
  unsigned int u = __float_as_uint(f);
  u = u + 0x7fffu + ((u >> 16) & 1u);
  return (unsigned short)(u >> 16);
}
__device__ __forceinline__ float b2f(unsigned short u) {
  return __uint_as_float((unsigned int)u << 16);
}
__device__ __forceinline__ float4 ld4h(const _Float16* p) {
  h16x4 h = *reinterpret_cast<const h16x4*>(p);
  return make_float4((float)h[0], (float)h[1], (float)h[2], (float)h[3]);
}

__device__ __forceinline__ f32x4 mfma_bf16(s16x8 a, s16x8 b, f32x4 c) {
  f32x4 d;
  asm volatile("v_mfma_f32_16x16x32_bf16 %0, %1, %2, %3"
               : "=&v"(d) : "v"(a), "v"(b), "v"(c));
  return d;
}

__device__ __forceinline__ float wave_bcast_sum(float v) {
#pragma unroll
  for (int off = 32; off > 0; off >>= 1) v += __shfl_down(v, off);
  return __shfl(v, 0);
}

// ---------------------------------------------------------------------------
// weight descs for fused convert (runs inside prep launch)
// ---------------------------------------------------------------------------
struct WDesc { const float* src; int K, N, Kp, dstOff, blkOff; };
struct WPack { WDesc d[11]; };

__device__ __forceinline__ void convert_w_body(const WPack& p, unsigned short* dst,
                                               int bi) {
  int mi = 0;
#pragma unroll
  for (int i = 1; i < 11; i++) if (bi >= p.d[i].blkOff) mi = i;
  WDesc w = p.d[mi];
  int e = (bi - w.blkOff) * 2048 + threadIdx.x * 8;
  int total = w.N * w.Kp;
  if (e >= total) return;
  int n = e / w.Kp, k0 = e - n * w.Kp;
  s16x8 pack;
#pragma unroll
  for (int j = 0; j < 8; j++) {
    int kk = k0 + j;
    float vv = (kk < w.K) ? w.src[(size_t)kk * w.N + n] : 0.f;
    pack[j] = (short)f2b(vv);
  }
  *reinterpret_cast<s16x8*>(dst + w.dstOff + e) = pack;
}

// ---------------------------------------------------------------------------
// GEMM epilogue helper: split destinations.
//   col <  colSplit -> out0 (f32 or bf16 per mode0), row stride colSplit,
//                      resid (stride colSplit) added here
//   col >= colSplit -> out1 fp16, row stride (N - colSplit)
// act: 0 none, 1 silu all, 3 silu on cols in [256,512)
// swapMode: 0 none, 1 all rows swapped, 2 swap iff n0 >= colSplit
// ---------------------------------------------------------------------------
__device__ __forceinline__ void gemm_store(
    float vv, int row, int col, int N, int colSplit,
    const float* __restrict__ bias, const float* __restrict__ resid,
    void* __restrict__ out0, void* __restrict__ out1, int mode0, int act) {
  if (bias) vv += bias[col];
  if (act == 1 || (act == 3 && col >= 256 && col < 512))
    vv = vv / (1.f + expf(-vv));
  if (col < colSplit) {
    if (resid) vv += resid[(size_t)row * colSplit + col];
    if (mode0)
      ((unsigned short*)out0)[(size_t)row * colSplit + col] = f2b(vv);
    else
      ((float*)out0)[(size_t)row * colSplit + col] = vv;
  } else {
    ((_Float16*)out1)[(size_t)row * (N - colSplit) + (col - colSplit)] =
        (_Float16)vv;
  }
}

// ---------------------------------------------------------------------------
// bf16 MFMA GEMM, 64x64 tile, 256 thr (4 waves x 32x32), BK=32
// ---------------------------------------------------------------------------
__global__ __launch_bounds__(256) void mfma_gemm_kernel(
    const unsigned short* __restrict__ A, int Kp,
    const unsigned short* __restrict__ Wt, int N,
    const float* __restrict__ bias, const float* __restrict__ resid,
    void* __restrict__ out0, void* __restrict__ out1, int colSplit,
    int mode0, int swapMode, int act) {
  __shared__ unsigned short As[64 * 40];
  __shared__ unsigned short Bs[64 * 40];
  int tid = threadIdx.x;
  int m0 = blockIdx.y * 64, n0 = blockIdx.x * 64;
  int lane = tid & 63, wv = tid >> 6;
  int wr = wv >> 1, wc = wv & 1;
  int lr = lane & 15, lk = (lane >> 4) * 8;
  int sr = tid >> 2, sk8 = (tid & 3) * 8;
  int am = m0 + sr;
  int swp = (swapMode == 1) || (swapMode == 2 && n0 >= colSplit);
  if (swp) am = (am < Mrows / 2) ? am + Mrows / 2 : am - Mrows / 2;
  const unsigned short* aptr = A + (size_t)am * Kp + sk8;
  int bn = n0 + sr;
  const unsigned short* bptr = (bn < N) ? Wt + (size_t)bn * Kp + sk8 : nullptr;
  f32x4 acc00 = {}, acc01 = {}, acc10 = {}, acc11 = {};
  for (int k0 = 0; k0 < Kp; k0 += 32) {
    s16x8 av = *reinterpret_cast<const s16x8*>(aptr + k0);
    s16x8 bv = {};
    if (bptr) bv = *reinterpret_cast<const s16x8*>(bptr + k0);
    *reinterpret_cast<s16x8*>(&As[sr * 40 + sk8]) = av;
    *reinterpret_cast<s16x8*>(&Bs[sr * 40 + sk8]) = bv;
    __syncthreads();
    s16x8 a0 = *reinterpret_cast<const s16x8*>(&As[(wr * 32 + lr) * 40 + lk]);
    s16x8 a1 = *reinterpret_cast<const s16x8*>(&As[(wr * 32 + 16 + lr) * 40 + lk]);
    s16x8 b0 = *reinterpret_cast<const s16x8*>(&Bs[(wc * 32 + lr) * 40 + lk]);
    s16x8 b1 = *reinterpret_cast<const s16x8*>(&Bs[(wc * 32 + 16 + lr) * 40 + lk]);
    acc00 = mfma_bf16(a0, b0, acc00);
    acc01 = mfma_bf16(a0, b1, acc01);
    acc10 = mfma_bf16(a1, b0, acc10);
    acc11 = mfma_bf16(a1, b1, acc11);
    __syncthreads();
  }
  int rowBase = m0 + wr * 32 + (lane >> 4) * 4;
  f32x4 accs[2][2] = {{acc00, acc01}, {acc10, acc11}};
#pragma unroll
  for (int fc = 0; fc < 2; fc++) {
    int col = n0 + wc * 32 + fc * 16 + lr;
    if (col >= N) continue;
#pragma unroll
    for (int fr = 0; fr < 2; fr++) {
#pragma unroll
      for (int r = 0; r < 4; r++) {
        int row = rowBase + fr * 16 + r;
        gemm_store(accs[fr][fc][r], row, col, N, colSplit, bias, resid,
                   out0, out1, mode0, act);
      }
    }
  }
}

// ---------------------------------------------------------------------------
// bf16 MFMA GEMM, 32x64 tile, 128 thr (2 waves x 32x32) — small N
// ---------------------------------------------------------------------------
__global__ __launch_bounds__(128) void mfma_gemm32_kernel(
    const unsigned short* __restrict__ A, int Kp,
    const unsigned short* __restrict__ Wt, int N,
    const float* __restrict__ bias, const float* __restrict__ resid,
    void* __restrict__ out0, void* __restrict__ out1, int colSplit,
    int mode0, int swapMode, int act) {
  __shared__ unsigned short As[32 * 40];
  __shared__ unsigned short Bs[64 * 40];
  int tid = threadIdx.x;
  int m0 = blockIdx.y * 32, n0 = blockIdx.x * 64;
  int lane = tid & 63, wv = tid >> 6;
  int lr = lane & 15, lk = (lane >> 4) * 8;
  int sr = tid >> 2, sk8 = (tid & 3) * 8;
  int am = m0 + sr;
  int swp = (swapMode == 1) || (swapMode == 2 && n0 >= colSplit);
  if (swp) am = (am < Mrows / 2) ? am + Mrows / 2 : am - Mrows / 2;
  const unsigned short* aptr = A + (size_t)am * Kp + sk8;
  int bn0 = n0 + sr, bn1 = n0 + sr + 32;
  const unsigned short* bptr0 = (bn0 < N) ? Wt + (size_t)bn0 * Kp + sk8 : nullptr;
  const unsigned short* bptr1 = (bn1 < N) ? Wt + (size_t)bn1 * Kp + sk8 : nullptr;
  f32x4 acc00 = {}, acc01 = {}, acc10 = {}, acc11 = {};
  for (int k0 = 0; k0 < Kp; k0 += 32) {
    s16x8 av = *reinterpret_cast<const s16x8*>(aptr + k0);
    s16x8 bv0 = {}, bv1 = {};
    if (bptr0) bv0 = *reinterpret_cast<const s16x8*>(bptr0 + k0);
    if (bptr1) bv1 = *reinterpret_cast<const s16x8*>(bptr1 + k0);
    *reinterpret_cast<s16x8*>(&As[sr * 40 + sk8]) = av;
    *reinterpret_cast<s16x8*>(&Bs[sr * 40 + sk8]) = bv0;
    *reinterpret_cast<s16x8*>(&Bs[(sr + 32) * 40 + sk8]) = bv1;
    __syncthreads();
    s16x8 a0 = *reinterpret_cast<const s16x8*>(&As[lr * 40 + lk]);
    s16x8 a1 = *reinterpret_cast<const s16x8*>(&As[(16 + lr) * 40 + lk]);
    s16x8 b0 = *reinterpret_cast<const s16x8*>(&Bs[(wv * 32 + lr) * 40 + lk]);
    s16x8 b1 = *reinterpret_cast<const s16x8*>(&Bs[(wv * 32 + 16 + lr) * 40 + lk]);
    acc00 = mfma_bf16(a0, b0, acc00);
    acc01 = mfma_bf16(a0, b1, acc01);
    acc10 = mfma_bf16(a1, b0, acc10);
    acc11 = mfma_bf16(a1, b1, acc11);
    __syncthreads();
  }
  int rowBase = m0 + (lane >> 4) * 4;
  f32x4 accs[2][2] = {{acc00, acc01}, {acc10, acc11}};
#pragma unroll
  for (int fc = 0; fc < 2; fc++) {
    int col = n0 + wv * 32 + fc * 16 + lr;
    if (col >= N) continue;
#pragma unroll
    for (int fr = 0; fr < 2; fr++) {
#pragma unroll
      for (int r = 0; r < 4; r++) {
        int row = rowBase + fr * 16 + r;
        gemm_store(accs[fr][fc][r], row, col, N, colSplit, bias, resid,
                   out0, out1, mode0, act);
      }
    }
  }
}

// ---------------------------------------------------------------------------
// prep (+ fused weight convert in first nconv blocks)
// ---------------------------------------------------------------------------
__global__ __launch_bounds__(256) void prep_kernel(
    WPack wp, unsigned short* __restrict__ warena, int nconv,
    const float* __restrict__ x, const float* __restrict__ rpos,
    const float* __restrict__ field, const float* __restrict__ fs,
    const float* __restrict__ n0g, const float* __restrict__ n0b,
    float* __restrict__ xc, unsigned short* __restrict__ xe_b) {
  if (blockIdx.x < (unsigned)nconv) {
    convert_w_body(wp, warena, blockIdx.x);
    return;
  }
  int wv = threadIdx.x >> 6, lane = threadIdx.x & 63;
  int pix = (blockIdx.x - nconv) * 4 + wv;
  int b = pix / Nn, n = pix - b * Nn;
  int py = n / Ww, px = n - py * Ww;
  const float* xrow = x + (size_t)pix * Cch;
  const float* rrow = rpos + (size_t)pix * 16;
  float f0 = field[(size_t)pix * 2 + 0], f1 = field[(size_t)pix * 2 + 1];
  float fsx = fs[0], fsy = fs[1];
  float vals[3];
#pragma unroll
  for (int i = 0; i < 3; i++) {
    int c = lane + i * 64;
    float v = 0.f;
    if (c < Cch) v = xrow[c];
    else if (c == 128) v = f0 * fsx;
    else if (c == 129) v = f1 * fsy;
    else if (c < DSELF) v = rrow[c - 130];
    vals[i] = v;
  }
  float* xcrow = xc + (size_t)pix * DSELF;
#pragma unroll
  for (int i = 0; i < 3; i++) {
    int c = lane + i * 64;
    if (c < DSELF) xcrow[c] = vals[i];
  }
  float s = 0.f;
#pragma unroll
  for (int i = 0; i < 3; i++) { int c = lane + i * 64; if (c < DSELF) s += vals[i]; }
  float mu = wave_bcast_sum(s) * (1.f / DSELF);
  float s2 = 0.f;
#pragma unroll
  for (int i = 0; i < 3; i++) {
    int c = lane + i * 64;
    if (c < DSELF) { float d = vals[i] - mu; s2 += d * d; }
  }
  float var = wave_bcast_sum(s2) * (1.f / DSELF);
  float rs = rsqrtf(var + 1e-5f);
  float noc = 0.f;
  if (lane == 0) {
    float ox = fminf(fmaxf(f0 + (float)px, 0.f), (float)(Ww - 1));
    float oy = fminf(fmaxf(f1 + (float)py, 0.f), (float)(Hh - 1));
    float x0f = fminf(fmaxf(floorf(ox), 0.f), (float)(Ww - 2));
    float y0f = fminf(fmaxf(floorf(oy), 0.f), (float)(Hh - 2));
    int x0 = (int)x0f, y0 = (int)y0f;
    float wx = ox - x0f, wy = oy - y0f;
    const float* fo = field + (size_t)(1 - b) * Nn * 2;
    const float* p00 = fo + ((size_t)y0 * Ww + x0) * 2;
    const float* p10 = fo + ((size_t)(y0 + 1) * Ww + x0) * 2;
    float v0 = (1.f - wy) * ((1.f - wx) * p00[0] + wx * p00[2]) +
               wy * ((1.f - wx) * p10[0] + wx * p10[2]);
    float v1 = (1.f - wy) * ((1.f - wx) * p00[1] + wx * p00[3]) +
               wy * ((1.f - wx) * p10[1] + wx * p10[3]);
    float diff = fabsf(f0 + v0) + fabsf(f1 + v1);
    noc = (diff < 2.f) ? 1.f : 0.f;
  }
  noc = __shfl(noc, 0);
  unsigned short* xerow = xe_b + (size_t)pix * 160;
#pragma unroll
  for (int i = 0; i < 3; i++) {
    int c = lane + i * 64;
    if (c < 160) {
      float v;
      if (c < DSELF) v = (vals[i] - mu) * rs * n0g[c] + n0b[c];
      else if (c == 146) v = noc;
      else v = 0.f;
      xerow[c] = f2b(v);
    }
  }
}

// ---------------------------------------------------------------------------
// windowed match attention, one WAVE per pixel.
// q (f32, stride qstride; optional gate at +gOff); k/v fp16 in kvbuf
// (stride 512, k at +0, v at +256). bf16 outputs.
// ---------------------------------------------------------------------------
__global__ __launch_bounds__(256) void attn_wave_kernel(
    const float* __restrict__ qbuf, int qstride, int gOff,
    const _Float16* __restrict__ kvbuf,
    const float* __restrict__ rpos, const float* __restrict__ xc2,
    const float* __restrict__ fs, unsigned short* __restrict__ o, int o_stride,
    int mode) {
  int wv = threadIdx.x >> 6, lane = threadIdx.x & 63;
  int pix = blockIdx.x * 4 + wv;
  int b = pix / Nn, n = pix - b * Nn;
  int py = n / Ww, px = n - py * Ww;
  int h = lane >> 3, c = lane & 7;
  size_t row = (size_t)pix;
  float ox, oy;
  if (mode == 0) {
    ox = rpos[row * 16 + 2 * h] + (float)px;
    oy = rpos[row * 16 + 2 * h + 1] + (float)py;
  } else {
    ox = xc2[row * DCROSS + 128] / fs[0] + (float)px;
    oy = (float)py;
  }
  ox = fminf(fmaxf(ox, 1.0f), 93.999f);
  oy = fminf(fmaxf(oy, 1.0f), 45.999f);
  float mxf = floorf(ox), myf = floorf(oy);
  float fx = ox - mxf, fy = oy - myf;
  int mx = (int)mxf, my = (int)myf;
  int base = b * Nn;

  float4 qv = *reinterpret_cast<const float4*>(qbuf + row * qstride + lane * 4);
  float s[16];
#pragma unroll
  for (int j = 0; j < 4; j++) {
    int gy = my - 1 + j;
#pragma unroll
    for (int i = 0; i < 4; i++) {
      int gx = mx - 1 + i;
      int idx = gy * Ww + gx;
      float4 kv = ld4h(kvbuf + (size_t)(base + idx) * 512 + lane * 4);
      float d = qv.x * kv.x + qv.y * kv.y + qv.z * kv.z + qv.w * kv.w;
      d += __shfl_xor(d, 1);
      d += __shfl_xor(d, 2);
      d += __shfl_xor(d, 4);
      s[j * 4 + i] = d * SCALEf;
    }
  }
  float w00 = (1.f - fy) * (1.f - fx), w01 = (1.f - fy) * fx;
  float w10 = fy * (1.f - fx), w11 = fy * fx;
  float sc[9];
#pragma unroll
  for (int j = 0; j < 3; j++)
#pragma unroll
    for (int i = 0; i < 3; i++)
      sc[j * 3 + i] = w00 * s[j * 4 + i] + w01 * s[j * 4 + i + 1] +
                      w10 * s[(j + 1) * 4 + i] + w11 * s[(j + 1) * 4 + i + 1];
  float mval = sc[0];
#pragma unroll
  for (int i = 1; i < 9; i++) mval = fmaxf(mval, sc[i]);
  float p[9], psum = 0.f;
#pragma unroll
  for (int i = 0; i < 9; i++) { p[i] = expf(sc[i] - mval); psum += p[i]; }
  float inv = 1.f / psum;
#pragma unroll
  for (int i = 0; i < 9; i++) p[i] *= inv;
  float Ag[16] = {};
#pragma unroll
  for (int j = 0; j < 3; j++)
#pragma unroll
    for (int i = 0; i < 3; i++) {
      float pv = p[j * 3 + i];
      Ag[j * 4 + i] += w00 * pv;
      Ag[j * 4 + i + 1] += w01 * pv;
      Ag[(j + 1) * 4 + i] += w10 * pv;
      Ag[(j + 1) * 4 + i + 1] += w11 * pv;
    }
  float4 acc = make_float4(0.f, 0.f, 0.f, 0.f);
#pragma unroll
  for (int j = 0; j < 4; j++) {
    int gy = my - 1 + j;
#pragma unroll
    for (int i = 0; i < 4; i++) {
      int gx = mx - 1 + i;
      int idx = gy * Ww + gx;
      float4 vv = ld4h(kvbuf + (size_t)(base + idx) * 512 + 256 + lane * 4);
      float w = Ag[j * 4 + i];
      acc.x += w * vv.x; acc.y += w * vv.y; acc.z += w * vv.z; acc.w += w * vv.w;
    }
  }
  if (gOff >= 0) {
    float4 gg = *reinterpret_cast<const float4*>(qbuf + row * qstride + gOff + lane * 4);
    acc.x *= gg.x; acc.y *= gg.y; acc.z *= gg.z; acc.w *= gg.w;
  }
  unsigned int p0 = (unsigned int)f2b(acc.x) | ((unsigned int)f2b(acc.y) << 16);
  unsigned int p1 = (unsigned int)f2b(acc.z) | ((unsigned int)f2b(acc.w) << 16);
  *reinterpret_cast<uint2*>(o + row * o_stride + lane * 4) = make_uint2(p0, p1);
  if (mode == 1) {
    float a0 = 0.f, a1 = 0.f;
#pragma unroll
    for (int a = 0; a < 8; a++) {
      if (c == a) { a0 = Ag[2 * a]; a1 = Ag[2 * a + 1]; }
    }
    unsigned int pa = (unsigned int)f2b(a0) | ((unsigned int)f2b(a1) << 16);
    *reinterpret_cast<unsigned int*>(o + row * o_stride + 256 + h * 16 + 2 * c) = pa;
  }
}

// ---------------------------------------------------------------------------
// post self-attn
// ---------------------------------------------------------------------------
__global__ __launch_bounds__(256) void post_self_kernel(
    const float* __restrict__ xcn, const float* __restrict__ n1g,
    const float* __restrict__ n1b, float* __restrict__ out_rpos,
    float* __restrict__ xc2, unsigned short* __restrict__ h1_b) {
  int wv = threadIdx.x >> 6, lane = threadIdx.x & 63;
  int pix = blockIdx.x * 4 + wv;
  const float* row = xcn + (size_t)pix * DSELF;
  float vals[3];
#pragma unroll
  for (int i = 0; i < 3; i++) {
    int c = lane + i * 64;
    vals[i] = (c < DSELF) ? row[c] : 0.f;
  }
#pragma unroll
  for (int i = 0; i < 3; i++) {
    int c = lane + i * 64;
    if (c >= 130 && c < 146) out_rpos[(size_t)pix * 16 + (c - 130)] = vals[i];
  }
#pragma unroll
  for (int i = 0; i < 3; i++) {
    int c = lane + i * 64;
    if (c == 129) vals[i] = 0.f;
  }
  float* x2row = xc2 + (size_t)pix * DCROSS;
#pragma unroll
  for (int i = 0; i < 3; i++) {
    int c = lane + i * 64;
    if (c < DCROSS) x2row[c] = vals[i];
  }
  float s = 0.f;
#pragma unroll
  for (int i = 0; i < 3; i++) { int c = lane + i * 64; if (c < DCROSS) s += vals[i]; }
  float mu = wave_bcast_sum(s) * (1.f / DCROSS);
  float s2 = 0.f;
#pragma unroll
  for (int i = 0; i < 3; i++) {
    int c = lane + i * 64;
    if (c < DCROSS) { float d = vals[i] - mu; s2 += d * d; }
  }
  float var = wave_bcast_sum(s2) * (1.f / DCROSS);
  float rs = rsqrtf(var + 1e-5f);
  unsigned short* h1row = h1_b + (size_t)pix * 160;
#pragma unroll
  for (int i = 0; i < 3; i++) {
    int c = lane + i * 64;
    if (c < 160) {
      float v = (c < DCROSS) ? (vals[i] - mu) * rs * n1g[c] + n1b[c] : 0.f;
      h1row[c] = f2b(v);
    }
  }
}

// ---------------------------------------------------------------------------
// post cross-attn
// ---------------------------------------------------------------------------
__global__ __launch_bounds__(256) void post_cross_kernel(
    const float* __restrict__ xc2n, const float* __restrict__ fs,
    const float* __restrict__ n2g, const float* __restrict__ n2b,
    float* __restrict__ out_f2, float* __restrict__ xob,
    unsigned short* __restrict__ h2_b) {
  int wv = threadIdx.x >> 6, lane = threadIdx.x & 63;
  int pix = blockIdx.x * 4 + wv;
  const float* row = xc2n + (size_t)pix * DCROSS;
  float vals[3];
#pragma unroll
  for (int i = 0; i < 3; i++) {
    int c = lane + i * 64;
    vals[i] = (c < DCROSS) ? row[c] : 0.f;
  }
  if (lane == 0) out_f2[(size_t)pix * 2 + 0] = vals[2] / fs[0];
  if (lane == 1) out_f2[(size_t)pix * 2 + 1] = 0.f;
  float* xrow = xob + (size_t)pix * Cch;
#pragma unroll
  for (int i = 0; i < 2; i++) {
    int c = lane + i * 64;
    xrow[c] = vals[i];
  }
  float s = vals[0] + vals[1];
  float mu = wave_bcast_sum(s) * (1.f / Cch);
  float d0 = vals[0] - mu, d1 = vals[1] - mu;
  float var = wave_bcast_sum(d0 * d0 + d1 * d1) * (1.f / Cch);
  float rs = rsqrtf(var + 1e-5f);
  unsigned short* h2row = h2_b + (size_t)pix * Cch;
#pragma unroll
  for (int i = 0; i < 2; i++) {
    int c = lane + i * 64;
    h2row[c] = f2b((vals[i] - mu) * rs * n2g[c] + n2b[c]);
  }
}

// ---------------------------------------------------------------------------
// depthwise 3x3 SAME on u_b[:, :256] (bf16), + bias, exact gelu, * gate -> bf16
// ---------------------------------------------------------------------------
__global__ __launch_bounds__(256) void dwconv_kernel(
    const unsigned short* __restrict__ ub, const float* __restrict__ dww,
    const float* __restrict__ dwb, unsigned short* __restrict__ aout) {
  int t = blockIdx.x * 256 + threadIdx.x;
  int c8 = (t & 31) * 8;
  int pix = t >> 5;
  int b = pix / Nn, n = pix - b * Nn;
  int py = n / Ww, px = n - py * Ww;
  float acc[8];
#pragma unroll
  for (int j = 0; j < 8; j++) acc[j] = dwb[c8 + j];
#pragma unroll
  for (int ky = 0; ky < 3; ky++) {
    int yy = py + ky - 1;
    if (yy < 0 || yy >= Hh) continue;
#pragma unroll
    for (int kx = 0; kx < 3; kx++) {
      int xx = px + kx - 1;
      if (xx < 0 || xx >= Ww) continue;
      s16x8 uv = *reinterpret_cast<const s16x8*>(
          ub + ((size_t)(b * Nn + yy * Ww + xx)) * 512 + c8);
      const float* wrow = dww + (ky * 3 + kx) * 256 + c8;
#pragma unroll
      for (int j = 0; j < 8; j++)
        acc[j] += b2f((unsigned short)uv[j]) * wrow[j];
    }
  }
  s16x8 gate = *reinterpret_cast<const s16x8*>(ub + (size_t)pix * 512 + 256 + c8);
  s16x8 outp;
#pragma unroll
  for (int j = 0; j < 8; j++) {
    float a = acc[j];
    float ge = 0.5f * a * (1.f + erff(a * 0.70710678118654752f));
    outp[j] = (short)f2b(ge * b2f((unsigned short)gate[j]));
  }
  *reinterpret_cast<s16x8*>(aout + (size_t)pix * 256 + c8) = outp;
}

extern "C" void kernel_launch(void* const* d_in, const int* in_sizes, int n_in,
                              void* d_out, int out_size, void* d_ws, size_t ws_size,
                              hipStream_t stream) {
  (void)in_sizes; (void)n_in; (void)out_size; (void)ws_size;
  const float* x    = (const float*)d_in[0];
  const float* rpos = (const float*)d_in[1];
  const float* field= (const float*)d_in[2];
  const float* fs   = (const float*)d_in[3];
  const float* n0g  = (const float*)d_in[4];
  const float* n0b  = (const float*)d_in[5];
  const float* n1g  = (const float*)d_in[6];
  const float* n1b  = (const float*)d_in[7];
  const float* n2g  = (const float*)d_in[8];
  const float* n2b  = (const float*)d_in[9];
  const float* sq_w = (const float*)d_in[10];
  const float* sk_w = (const float*)d_in[11];
  const float* sv_w = (const float*)d_in[12];
  const float* sp_w = (const float*)d_in[13];
  const float* cq_w = (const float*)d_in[14];
  const float* ck_w = (const float*)d_in[15];
  const float* cv_w = (const float*)d_in[16];
  const float* cg_w = (const float*)d_in[17];
  const float* cp_w = (const float*)d_in[18];
  const float* fc1w = (const float*)d_in[19];
  const float* fc1b = (const float*)d_in[20];
  const float* dww  = (const float*)d_in[21];
  const float* dwb  = (const float*)d_in[22];
  const float* fc2w = (const float*)d_in[23];
  const float* fc2b = (const float*)d_in[24];

  float* ws = (float*)d_ws;
  float* xc    = ws + 0;         // 1345536
  float* xcn   = ws + 1345536;   // 1345536 -> 2691072
  float* xc2   = ws + 2691072;   // 1198080 -> 3889152
  float* xc2n  = ws + 3889152;   // 1198080 -> 5087232
  float* xob   = ws + 5087232;   // 1179648 -> 6266880
  unsigned short* xe_b = (unsigned short*)(ws + 6266880);  // 737280 -> 7004160
  unsigned short* h1_b = (unsigned short*)(ws + 7004160);  // 737280 -> 7741440
  unsigned short* h2_b = (unsigned short*)(ws + 7741440);  // 589824 -> 8331264
  float* q32   = ws + 8331264;   // 2359296 -> 10690560
  _Float16* kv16 = (_Float16*)(ws + 10690560);  // 2359296 -> 13049856
  float* qg    = ws + 13049856;  // 4718592 -> 17768448
  unsigned short* o_b    = (unsigned short*)(ws + 17768448);  // 1179648 -> 18948096
  unsigned short* ocat_b = (unsigned short*)(ws + 18948096);  // 1769472 -> 20717568
  unsigned short* warena = (unsigned short*)(ws + 20717568);  // 236160 -> 20953728
  unsigned short* u_b    = (unsigned short*)qg;  // qg dead after cross attn
  unsigned short* aconv_b = o_b;                 // o_b dead after sp GEMM

  float* out_xo   = (float*)d_out;
  float* out_rpos = out_xo + 1179648;
  float* out_f2   = out_xo + 1327104;

  const int oSQKV = 0;          // 768*160
  const int oSP   = 122880;     // 146*256
  const int oCQGKV= 160256;     // 1024*160
  const int oCP   = 324096;     // 130*384
  const int oF1   = 374016;     // 512*128
  const int oF2   = 439552;     // 128*256 (ends 472320)
  WPack wp;
  auto setw = [&](int i, const float* src, int K, int N, int Kp, int off) {
    wp.d[i].src = src; wp.d[i].K = K; wp.d[i].N = N; wp.d[i].Kp = Kp;
    wp.d[i].dstOff = off;
  };
  setw(0, sq_w, 147, 256, 160, oSQKV);
  setw(1, sk_w, 147, 256, 160, oSQKV + 40960);
  setw(2, sv_w, 147, 256, 160, oSQKV + 81920);
  setw(3, sp_w, 256, 146, 256, oSP);
  setw(4, cq_w, 130, 256, 160, oCQGKV);
  setw(5, cg_w, 130, 256, 160, oCQGKV + 40960);
  setw(6, ck_w, 130, 256, 160, oCQGKV + 81920);
  setw(7, cv_w, 130, 256, 160, oCQGKV + 122880);
  setw(8, cp_w, 384, 130, 384, oCP);
  setw(9, fc1w, 128, 512, 128, oF1);
  setw(10, fc2w, 256, 128, 256, oF2);
  int nblk = 0;
  for (int i = 0; i < 11; i++) {
    wp.d[i].blkOff = nblk;
    nblk += (wp.d[i].N * wp.d[i].Kp + 2047) / 2048;
  }

  dim3 blk(256);
  auto gemm = [&](const unsigned short* A, int Kp, int woff, int N,
                  const float* bias, const float* resid, void* out0, void* out1,
                  int colSplit, int mode0, int swapMode, int act) {
    if (N <= 384) {
      dim3 grid((N + 63) / 64, Mrows / 32);
      mfma_gemm32_kernel<<<grid, dim3(128), 0, stream>>>(
          A, Kp, warena + woff, N, bias, resid, out0, out1, colSplit, mode0,
          swapMode, act);
    } else {
      dim3 grid((N + 63) / 64, Mrows / 64);
      mfma_gemm_kernel<<<grid, blk, 0, stream>>>(
          A, Kp, warena + woff, N, bias, resid, out0, out1, colSplit, mode0,
          swapMode, act);
    }
  };

  // 1. prep + fused weight conversion
  prep_kernel<<<nblk + 2304, blk, 0, stream>>>(wp, warena, nblk, x, rpos, field,
                                               fs, n0g, n0b, xc, xe_b);
  // 2. self QKV: q -> q32 (f32), k|v -> kv16 (fp16)
  gemm(xe_b, 160, oSQKV, 768, nullptr, nullptr, q32, kv16, 256, 0, 0, 0);
  // 3. self attention
  attn_wave_kernel<<<2304, blk, 0, stream>>>(q32, 256, -1, kv16, rpos, nullptr,
                                             fs, o_b, 256, 0);
  // 4. sp projection + residual
  gemm(o_b, 256, oSP, 146, nullptr, xc, xcn, nullptr, 146, 0, 0, 0);
  // 5. post-self
  post_self_kernel<<<2304, blk, 0, stream>>>(xcn, n1g, n1b, out_rpos, xc2, h1_b);
  // 6. cross q|g|k|v fused: q,g -> qg (f32, silu on [256,512)), k|v -> kv16
  gemm(h1_b, 160, oCQGKV, 1024, nullptr, nullptr, qg, kv16, 512, 0, 2, 3);
  // 7. cross attention (gated, writes Af)
  attn_wave_kernel<<<2304, blk, 0, stream>>>(qg, 512, 256, kv16, nullptr, xc2,
                                             fs, ocat_b, 384, 1);
  // 8. cp projection + residual
  gemm(ocat_b, 384, oCP, 130, nullptr, xc2, xc2n, nullptr, 130, 0, 0, 0);
  // 9. post-cross
  post_cross_kernel<<<2304, blk, 0, stream>>>(xc2n, fs, n2g, n2b, out_f2, xob, h2_b);
  // 10. fc1 -> u bf16
  gemm(h2_b, 128, oF1, 512, fc1b, nullptr, u_b, nullptr, 512, 1, 0, 0);
  // 11. depthwise conv + gelu + gate
  dwconv_kernel<<<1152, blk, 0, stream>>>(u_b, dww, dwb, aconv_b);
  // 12. fc2 + residual
  gemm(aconv_b, 256, oF2, 128, fc2b, xob, out_xo, nullptr, 128, 0, 0, 0);
}